// Round 2
// baseline (2215.778 us; speedup 1.0000x reference)
//
#include <hip/hip_runtime.h>
#include <hip/hip_bf16.h>

// ACLSTM on MI355X — persistent-RNN design, time-chunked to fit ws_size.
// K0: quantize W_hh / W_logit / W_value to int8 (per-row scale).
// K1 (per chunk): xp = features @ W_ih^T + (b_ih+b_hh), bf16, gate-interleaved
//     layout [t][s][j][gm] for coalesced K2 reads.
// K2 (per chunk): 16 persistent blocks (16 seqs each), 8 waves, Tc serial steps.
//     W_hh int8 register-resident (128 VGPR/lane), h int8 in LDS ping-pong,
//     c fp32 in registers, fused logit/value heads (lag-1), int8 MFMA.
//     h/c carried across chunks via ws (h requantized -> identical numerics).

typedef float f32x4 __attribute__((ext_vector_type(4)));
typedef int   i32x4 __attribute__((ext_vector_type(4)));
typedef short s16x8 __attribute__((ext_vector_type(8)));
typedef short s16x4 __attribute__((ext_vector_type(4)));
typedef unsigned short u16x4 __attribute__((ext_vector_type(4)));

#define L2E  1.44269504088896340736f
#define L2E2 2.88539008177792681472f

__device__ __forceinline__ float sigm(float x) {
  return __builtin_amdgcn_rcpf(1.f + exp2f(-L2E * x));
}
__device__ __forceinline__ float tanh_f(float x) {
  return 1.f - 2.f * __builtin_amdgcn_rcpf(1.f + exp2f(L2E2 * x));
}
__device__ __forceinline__ float bf2f(unsigned short u) {
  return __uint_as_float(((unsigned)u) << 16);
}
__device__ __forceinline__ unsigned short f2bf(float f) {   // RNE f32->bf16
  unsigned int b = __float_as_uint(f);
  return (unsigned short)((b + 0x7FFFu + ((b >> 16) & 1u)) >> 16);
}

// ---------------------------------------------------------------- K0: quant
__global__ void k0_quant(const float* __restrict__ Whh,
                         const float* __restrict__ Wlog,
                         const float* __restrict__ Wval,
                         signed char* __restrict__ Wq, float* __restrict__ wsc,
                         signed char* __restrict__ Wlq, float* __restrict__ lsc) {
  int r = blockIdx.x, l = threadIdx.x;   // 1057 rows, 64 lanes
  const float* src; signed char* dst; float* sd;
  if (r < 1024) { src = Whh + (size_t)r * 256; dst = Wq + (size_t)r * 256; sd = wsc + r; }
  else {
    int hr = r - 1024;
    src = (hr < 32) ? (Wlog + (size_t)hr * 256) : Wval;
    dst = Wlq + (size_t)hr * 256; sd = lsc + hr;
  }
  f32x4 v = *(const f32x4*)(src + l * 4);
  float m = fmaxf(fmaxf(fabsf(v.x), fabsf(v.y)), fmaxf(fabsf(v.z), fabsf(v.w)));
  #pragma unroll
  for (int off = 32; off; off >>= 1) m = fmaxf(m, __shfl_xor(m, off));
  float inv = (m > 0.f) ? (127.f / m) : 0.f;
  int q0 = (int)rintf(v.x * inv), q1 = (int)rintf(v.y * inv);
  int q2 = (int)rintf(v.z * inv), q3 = (int)rintf(v.w * inv);
  unsigned int pk = (q0 & 255) | ((q1 & 255) << 8) | ((q2 & 255) << 16) | ((q3 & 255) << 24);
  *(unsigned int*)(dst + l * 4) = pk;
  if (l == 0) *sd = m * (1.f / 127.f);
}

// ------------------------------------------------------------- K1: x_proj
// Chunk-local m = lt*256+s, lt = t - t0. Output layout: xp[(m*256+j)*4+gm],
// gate col g = gm*256+j. A row m -> features[(s*512 + t0+lt)*128 + k].
__launch_bounds__(256)
__global__ void k1_inproj(const float* __restrict__ feat,
                          const float* __restrict__ Wih,
                          const float* __restrict__ bih,
                          const float* __restrict__ bhh,
                          unsigned short* __restrict__ xp, int t0) {
  __shared__ short Al[64][136];     // 272B rows: 17*16 -> aligned + bank-rotated
  __shared__ short Bl[128][136];
  __shared__ float bias[128];
  int tid = threadIdx.x;
  int bm = blockIdx.x >> 3, bn = blockIdx.x & 7;
  int m0 = bm << 6, n0 = bn << 7;
  int tg = t0 + (m0 >> 8), sbase = m0 & 255;   // 64 | 256 => single t per tile
  #pragma unroll
  for (int it = 0; it < 8; ++it) {             // A: 64x128 f32 -> bf16
    int idx = it * 256 + tid;
    int row = idx >> 5, c4 = (idx & 31) << 2;
    f32x4 v = *(const f32x4*)(feat + ((size_t)(sbase + row) * 512 + tg) * 128 + c4);
    s16x4 pk = { (short)f2bf(v.x), (short)f2bf(v.y), (short)f2bf(v.z), (short)f2bf(v.w) };
    *(s16x4*)&Al[row][c4] = pk;
  }
  #pragma unroll
  for (int it = 0; it < 16; ++it) {            // B: 128x128 (W_ih rows = gate cols)
    int idx = it * 256 + tid;
    int row = idx >> 5, c4 = (idx & 31) << 2;
    f32x4 v = *(const f32x4*)(Wih + (size_t)(n0 + row) * 128 + c4);
    s16x4 pk = { (short)f2bf(v.x), (short)f2bf(v.y), (short)f2bf(v.z), (short)f2bf(v.w) };
    *(s16x4*)&Bl[row][c4] = pk;
  }
  if (tid < 128) bias[tid] = bih[n0 + tid] + bhh[n0 + tid];
  __syncthreads();
  int w = tid >> 6, l = tid & 63;
  int wm = w >> 1, wn = w & 1;                 // 2x2 wave grid: 32m x 64n per wave
  int lr = l & 15, lk = (l >> 4) << 3;
  f32x4 z = {0.f, 0.f, 0.f, 0.f};
  f32x4 acc[2][4];
  #pragma unroll
  for (int mt = 0; mt < 2; ++mt)
    #pragma unroll
    for (int nt = 0; nt < 4; ++nt) acc[mt][nt] = z;
  #pragma unroll
  for (int kk = 0; kk < 4; ++kk) {
    s16x8 a0 = *(const s16x8*)&Al[wm * 32 + lr][kk * 32 + lk];
    s16x8 a1 = *(const s16x8*)&Al[wm * 32 + 16 + lr][kk * 32 + lk];
    #pragma unroll
    for (int nt = 0; nt < 4; ++nt) {
      s16x8 bb = *(const s16x8*)&Bl[wn * 64 + nt * 16 + lr][kk * 32 + lk];
      acc[0][nt] = __builtin_amdgcn_mfma_f32_16x16x32_bf16(a0, bb, acc[0][nt], 0, 0, 0);
      acc[1][nt] = __builtin_amdgcn_mfma_f32_16x16x32_bf16(a1, bb, acc[1][nt], 0, 0, 0);
    }
  }
  #pragma unroll
  for (int mt = 0; mt < 2; ++mt)
    #pragma unroll
    for (int nt = 0; nt < 4; ++nt)
      #pragma unroll
      for (int r = 0; r < 4; ++r) {
        int m = m0 + wm * 32 + mt * 16 + (l >> 4) * 4 + r;   // chunk-local
        int g = n0 + wn * 64 + nt * 16 + lr;                 // global gate col
        int gm = g >> 8, j = g & 255;
        float val = acc[mt][nt][r] + bias[g - n0];
        xp[((size_t)m * 256 + j) * 4 + gm] = f2bf(val);
      }
}

// ------------------------------------------------------------ K2: recurrence
// 16 blocks x 512 threads, Tc steps. Wave w owns h-cols [32w,32w+32) x 4 gates.
// tau = gamma*2 + half: gate col g = gamma*256 + 32w + half*16 + (lane&15).
__launch_bounds__(512, 2)
__global__ void k2_lstm(const unsigned short* __restrict__ xp,   // chunk base
                        const signed char* __restrict__ Wq,
                        const float* __restrict__ wsc,
                        const signed char* __restrict__ Wlq,
                        const float* __restrict__ lsc,
                        const float* __restrict__ ep,
                        const float* __restrict__ h0,
                        const float* __restrict__ c0,
                        const float* __restrict__ blog,
                        const float* __restrict__ bval,
                        float* __restrict__ hstate,
                        float* __restrict__ cstate,
                        float* __restrict__ out, int t0, int tc) {
  __shared__ signed char Hl[2][16][272];   // h int8, ping-pong, padded rows
  __shared__ signed char Wl[34][272];      // heads weights (32 logit + value + zero)
  __shared__ float flg[2][16];             // episode-start flags
  const int tid = threadIdx.x;
  const int w = tid >> 6, l = tid & 63;
  const int lc = l & 15, lq = l >> 4;
  const int s0 = (int)blockIdx.x << 4;
  const bool last = (t0 + tc == 512);

  for (int it = 0; it < 5; ++it) {         // stage heads weights
    int idx = it * 512 + tid;
    if (idx < 34 * 64) {
      int row = idx >> 6, c = (idx & 63) << 2;
      int v = (row < 33) ? *(const int*)(Wlq + (size_t)row * 256 + c) : 0;
      *(int*)&Wl[row][c] = v;
    }
  }
  {                                        // stage h (quantized int8)
    const float* hsrc = (t0 == 0) ? h0 : hstate;
    #pragma unroll
    for (int it = 0; it < 8; ++it) {
      int idx = it * 512 + tid;
      int s = idx >> 8, j = idx & 255;
      float v = hsrc[(size_t)(s0 + s) * 256 + j];
      float q = rintf(fminf(fmaxf(v * 127.f, -127.f), 127.f));
      Hl[0][s][j] = (signed char)(int)q;
    }
  }
  if (tid < 16) flg[0][tid] = ep[(size_t)(s0 + tid) * 512 + t0];

  i32x4 wq[8][4];                          // persistent int8 W_hh fragments
  float dsc[8];
  #pragma unroll
  for (int tau = 0; tau < 8; ++tau) {
    int g = (tau >> 1) * 256 + (w << 5) + ((tau & 1) << 4) + lc;
    #pragma unroll
    for (int kk = 0; kk < 4; ++kk)
      wq[tau][kk] = *(const i32x4*)(Wq + (size_t)g * 256 + kk * 64 + (lq << 4));
    dsc[tau] = wsc[g] * (1.f / 127.f);
  }
  int lrow; float lb, dls;                 // heads per-lane constants
  if (lc < 4)       { lrow = (w << 2) + lc; lb = blog[lrow]; dls = lsc[lrow] * (1.f / 127.f); }
  else if (lc == 4) { lrow = 32; lb = bval[0]; dls = lsc[32] * (1.f / 127.f); }
  else              { lrow = 33; lb = 0.f; dls = 0.f; }

  float cst[8];                            // c state fp32 (cell = half*4 + r)
  {
    const float* csrc = (t0 == 0) ? c0 : cstate;
    #pragma unroll
    for (int half = 0; half < 2; ++half)
      #pragma unroll
      for (int r = 0; r < 4; ++r)
        cst[half * 4 + r] = csrc[(size_t)(s0 + lq * 4 + r) * 256 + (w << 5) + (half << 4) + lc];
  }

  // xp per-lane element offset: ((lt*256 + s)*256 + j)*4 + gm ; s=s0+lq*4+r, j=w*32+half*16+lc
  const size_t xoff = ((size_t)(s0 + lq * 4) * 256 + (w << 5) + lc) * 4;
  u16x4 xq[8];
  {
    const unsigned short* pp = xp + xoff;  // lt = 0
    #pragma unroll
    for (int half = 0; half < 2; ++half)
      #pragma unroll
      for (int r = 0; r < 4; ++r)
        xq[half * 4 + r] = *(const u16x4*)(pp + r * 1024 + half * 64);
  }
  __syncthreads();

  i32x4 wlf[4];                            // heads B-fragments (loop-invariant)
  #pragma unroll
  for (int kk = 0; kk < 4; ++kk)
    wlf[kk] = *(const i32x4*)&Wl[lrow][kk * 64 + (lq << 4)];

  const int aoff  = lc * 272 + (lq << 4);            // A-frag lane offset (row=seq)
  const int hwoff = (lq * 4) * 272 + (w << 5) + lc;  // h-write lane offset
  const i32x4 zero4 = {0, 0, 0, 0};

  for (int lt = 0; lt < tc; ++lt) {
    const int p = lt & 1;
    const int t = t0 + lt;
    const signed char* hbase = &Hl[p][0][0];
    float fa = flg[p][lc];                 // reset flag for this lane's A row (seq)
    i32x4 racc[8];
    #pragma unroll
    for (int tau = 0; tau < 8; ++tau) racc[tau] = zero4;
    i32x4 hacc = zero4;
    #pragma unroll
    for (int kk = 0; kk < 4; ++kk) {
      i32x4 a = *(const i32x4*)(hbase + aoff + kk * 64);
      hacc = __builtin_amdgcn_mfma_i32_16x16x64_i8(a, wlf[kk], hacc, 0, 0, 0);  // heads (unmasked)
      i32x4 am = (fa != 0.f) ? zero4 : a;                                       // recurrent mask
      #pragma unroll
      for (int tau = 0; tau < 8; ++tau)
        racc[tau] = __builtin_amdgcn_mfma_i32_16x16x64_i8(am, wq[tau][kk], racc[tau], 0, 0, 0);
    }
    if (lt > 0) {                          // store heads for t-1
      #pragma unroll
      for (int r = 0; r < 4; ++r) {
        float v = lb + (float)hacc[r] * dls;
        int sg = s0 + lq * 4 + r;
        if (lc < 4)
          out[((size_t)sg * 512 + (t - 1)) * 32 + lrow] = v;
        else if (lc == 4 && w == 0)
          out[4194304 + (size_t)sg * 512 + (t - 1)] = v;
      }
    }
    float frr[4];
    #pragma unroll
    for (int r = 0; r < 4; ++r) frr[r] = flg[p][lq * 4 + r];
    signed char* hw = &Hl[p ^ 1][0][0];
    #pragma unroll
    for (int half = 0; half < 2; ++half) {
      #pragma unroll
      for (int r = 0; r < 4; ++r) {
        int cell = half * 4 + r;
        u16x4 xv = xq[cell];
        float gi = bf2f(xv.x) + (float)racc[0 + half][r] * dsc[0 + half];
        float gf = bf2f(xv.y) + (float)racc[2 + half][r] * dsc[2 + half];
        float gg = bf2f(xv.z) + (float)racc[4 + half][r] * dsc[4 + half];
        float go = bf2f(xv.w) + (float)racc[6 + half][r] * dsc[6 + half];
        float si = sigm(gi), sf = sigm(gf), so = sigm(go), tg = tanh_f(gg);
        float cp = (frr[r] != 0.f) ? 0.f : cst[cell];
        float cn = sf * cp + si * tg;
        cst[cell] = cn;
        float hn = so * tanh_f(cn);
        hw[hwoff + r * 272 + (half << 4)] = (signed char)(int)rintf(hn * 127.f);
        if (lt == tc - 1) {
          int sg = s0 + lq * 4 + r;
          int j = (w << 5) + (half << 4) + lc;
          hstate[(size_t)sg * 256 + j] = hn;
          cstate[(size_t)sg * 256 + j] = cn;
          if (last) {
            out[4325376 + (size_t)sg * 256 + j] = hn;   // final h (fp32)
            out[4390912 + (size_t)sg * 256 + j] = cn;   // final c
          }
        }
      }
    }
    if (lt < tc - 1) {
      if (tid < 16) flg[p ^ 1][tid] = ep[(size_t)(s0 + tid) * 512 + t + 1];
      const unsigned short* pp = xp + (size_t)(lt + 1) * 262144 + xoff;
      #pragma unroll
      for (int half = 0; half < 2; ++half)
        #pragma unroll
        for (int r = 0; r < 4; ++r)
          xq[half * 4 + r] = *(const u16x4*)(pp + r * 1024 + half * 64);
    }
    __syncthreads();
  }
  // epilogue: heads for t = t0+tc-1 (h lives in Hl[tc & 1])
  {
    i32x4 hacc = zero4;
    const signed char* hbase = &Hl[tc & 1][0][0];
    #pragma unroll
    for (int kk = 0; kk < 4; ++kk) {
      i32x4 a = *(const i32x4*)(hbase + aoff + kk * 64);
      hacc = __builtin_amdgcn_mfma_i32_16x16x64_i8(a, wlf[kk], hacc, 0, 0, 0);
    }
    #pragma unroll
    for (int r = 0; r < 4; ++r) {
      float v = lb + (float)hacc[r] * dls;
      int sg = s0 + lq * 4 + r;
      if (lc < 4)
        out[((size_t)sg * 512 + (t0 + tc - 1)) * 32 + lrow] = v;
      else if (lc == 4 && w == 0)
        out[4194304 + (size_t)sg * 512 + (t0 + tc - 1)] = v;
    }
  }
}

// ---------------------------------------------------------------- launcher
extern "C" void kernel_launch(void* const* d_in, const int* in_sizes, int n_in,
                              void* d_out, int out_size, void* d_ws, size_t ws_size,
                              hipStream_t stream) {
  const float* feat = (const float*)d_in[0];
  const float* ep   = (const float*)d_in[1];
  const float* h0   = (const float*)d_in[2];
  const float* c0   = (const float*)d_in[3];
  const float* Wih  = (const float*)d_in[4];
  const float* Whh  = (const float*)d_in[5];
  const float* bih  = (const float*)d_in[6];
  const float* bhh  = (const float*)d_in[7];
  const float* Wlog = (const float*)d_in[8];
  const float* blog = (const float*)d_in[9];
  const float* Wval = (const float*)d_in[10];
  const float* bval = (const float*)d_in[11];
  float* out = (float*)d_out;
  char* ws = (char*)d_ws;
  // ws layout (small buffers FIRST, xp chunk after 1 MiB):
  signed char* Wq     = (signed char*)(ws + 0);        // 262144
  float*       wsc    = (float*)      (ws + 262144);   // 4096
  signed char* Wlq    = (signed char*)(ws + 266240);   // 8448
  float*       lsc    = (float*)      (ws + 274688);   // 132
  float*       hstate = (float*)      (ws + 275456);   // 262144
  float*       cstate = (float*)      (ws + 537600);   // 262144 (ends 799744)
  unsigned short* xp  = (unsigned short*)(ws + 1048576);

  // Largest chunk Tc with 1 MiB + Tc*512 KiB <= ws_size (deterministic).
  int Tc = 512;
  while (Tc > 32 && (size_t)1048576 + (size_t)Tc * 524288 > ws_size) Tc >>= 1;

  hipLaunchKernelGGL(k0_quant, dim3(1057), dim3(64), 0, stream,
                     Whh, Wlog, Wval, Wq, wsc, Wlq, lsc);
  for (int t0 = 0; t0 < 512; t0 += Tc) {
    hipLaunchKernelGGL(k1_inproj, dim3(Tc * 32), dim3(256), 0, stream,
                       feat, Wih, bih, bhh, xp, t0);
    hipLaunchKernelGGL(k2_lstm, dim3(16), dim3(512), 0, stream,
                       xp, Wq, wsc, Wlq, lsc, ep, h0, c0, blog, bval,
                       hstate, cstate, out, t0, Tc);
  }
}

// Round 3
// 2106.142 us; speedup vs baseline: 1.0521x; 1.0521x over previous
//
#include <hip/hip_runtime.h>
#include <hip/hip_bf16.h>

// ACLSTM on MI355X — persistent-RNN design, time-chunked to fit ws_size.
// R3: K2 instruction diet — chunk-preloaded flags in LDS (no per-step global
//     flag load), early double-buffered xp prefetch (latency hidden under
//     MFMA+gate phase), raw v_exp_f32, gate pre-scaling folded into K1 output
//     (xp stores -log2e*x for i,f,o and 2log2e*x for g).

typedef float f32x4 __attribute__((ext_vector_type(4)));
typedef int   i32x4 __attribute__((ext_vector_type(4)));
typedef short s16x8 __attribute__((ext_vector_type(8)));
typedef short s16x4 __attribute__((ext_vector_type(4)));
typedef unsigned short u16x4 __attribute__((ext_vector_type(4)));

#define L2E  1.44269504088896340736f
#define L2E2 2.88539008177792681472f

__device__ __forceinline__ float fexp2(float x) {
#if __has_builtin(__builtin_amdgcn_exp2f)
  return __builtin_amdgcn_exp2f(x);
#else
  float r; asm("v_exp_f32 %0, %1" : "=v"(r) : "v"(x)); return r;
#endif
}
__device__ __forceinline__ float frcp(float x) { return __builtin_amdgcn_rcpf(x); }
__device__ __forceinline__ float bf2f(unsigned short u) {
  return __uint_as_float(((unsigned)u) << 16);
}
__device__ __forceinline__ unsigned short f2bf(float f) {   // RNE f32->bf16
  unsigned int b = __float_as_uint(f);
  return (unsigned short)((b + 0x7FFFu + ((b >> 16) & 1u)) >> 16);
}

// ---------------------------------------------------------------- K0: quant
__global__ void k0_quant(const float* __restrict__ Whh,
                         const float* __restrict__ Wlog,
                         const float* __restrict__ Wval,
                         signed char* __restrict__ Wq, float* __restrict__ wsc,
                         signed char* __restrict__ Wlq, float* __restrict__ lsc) {
  int r = blockIdx.x, l = threadIdx.x;   // 1057 rows, 64 lanes
  const float* src; signed char* dst; float* sd;
  if (r < 1024) { src = Whh + (size_t)r * 256; dst = Wq + (size_t)r * 256; sd = wsc + r; }
  else {
    int hr = r - 1024;
    src = (hr < 32) ? (Wlog + (size_t)hr * 256) : Wval;
    dst = Wlq + (size_t)hr * 256; sd = lsc + hr;
  }
  f32x4 v = *(const f32x4*)(src + l * 4);
  float m = fmaxf(fmaxf(fabsf(v.x), fabsf(v.y)), fmaxf(fabsf(v.z), fabsf(v.w)));
  #pragma unroll
  for (int off = 32; off; off >>= 1) m = fmaxf(m, __shfl_xor(m, off));
  float inv = (m > 0.f) ? (127.f / m) : 0.f;
  int q0 = (int)rintf(v.x * inv), q1 = (int)rintf(v.y * inv);
  int q2 = (int)rintf(v.z * inv), q3 = (int)rintf(v.w * inv);
  unsigned int pk = (q0 & 255) | ((q1 & 255) << 8) | ((q2 & 255) << 16) | ((q3 & 255) << 24);
  *(unsigned int*)(dst + l * 4) = pk;
  if (l == 0) *sd = m * (1.f / 127.f);
}

// ------------------------------------------------------------- K1: x_proj
// Chunk-local m = lt*256+s. Output: xp[(m*256+j)*4+gm], gate col g = gm*256+j.
// Stored PRE-SCALED: (x+b)*(-L2E) for gm in {0,1,3}, (x+b)*L2E2 for gm==2.
__launch_bounds__(256)
__global__ void k1_inproj(const float* __restrict__ feat,
                          const float* __restrict__ Wih,
                          const float* __restrict__ bih,
                          const float* __restrict__ bhh,
                          unsigned short* __restrict__ xp, int t0) {
  __shared__ short Al[64][136];
  __shared__ short Bl[128][136];
  __shared__ float bias[128];
  int tid = threadIdx.x;
  int bm = blockIdx.x >> 3, bn = blockIdx.x & 7;
  int m0 = bm << 6, n0 = bn << 7;
  int tg = t0 + (m0 >> 8), sbase = m0 & 255;   // 64 | 256 => single t per tile
  const float gsc = ((n0 >> 8) == 2) ? L2E2 : -L2E;  // gate scale, const per block
  #pragma unroll
  for (int it = 0; it < 8; ++it) {             // A: 64x128 f32 -> bf16
    int idx = it * 256 + tid;
    int row = idx >> 5, c4 = (idx & 31) << 2;
    f32x4 v = *(const f32x4*)(feat + ((size_t)(sbase + row) * 512 + tg) * 128 + c4);
    s16x4 pk = { (short)f2bf(v.x), (short)f2bf(v.y), (short)f2bf(v.z), (short)f2bf(v.w) };
    *(s16x4*)&Al[row][c4] = pk;
  }
  #pragma unroll
  for (int it = 0; it < 16; ++it) {            // B: 128x128 (W_ih rows = gate cols)
    int idx = it * 256 + tid;
    int row = idx >> 5, c4 = (idx & 31) << 2;
    f32x4 v = *(const f32x4*)(Wih + (size_t)(n0 + row) * 128 + c4);
    s16x4 pk = { (short)f2bf(v.x), (short)f2bf(v.y), (short)f2bf(v.z), (short)f2bf(v.w) };
    *(s16x4*)&Bl[row][c4] = pk;
  }
  if (tid < 128) bias[tid] = bih[n0 + tid] + bhh[n0 + tid];
  __syncthreads();
  int w = tid >> 6, l = tid & 63;
  int wm = w >> 1, wn = w & 1;                 // 2x2 wave grid: 32m x 64n per wave
  int lr = l & 15, lk = (l >> 4) << 3;
  f32x4 z = {0.f, 0.f, 0.f, 0.f};
  f32x4 acc[2][4];
  #pragma unroll
  for (int mt = 0; mt < 2; ++mt)
    #pragma unroll
    for (int nt = 0; nt < 4; ++nt) acc[mt][nt] = z;
  #pragma unroll
  for (int kk = 0; kk < 4; ++kk) {
    s16x8 a0 = *(const s16x8*)&Al[wm * 32 + lr][kk * 32 + lk];
    s16x8 a1 = *(const s16x8*)&Al[wm * 32 + 16 + lr][kk * 32 + lk];
    #pragma unroll
    for (int nt = 0; nt < 4; ++nt) {
      s16x8 bb = *(const s16x8*)&Bl[wn * 64 + nt * 16 + lr][kk * 32 + lk];
      acc[0][nt] = __builtin_amdgcn_mfma_f32_16x16x32_bf16(a0, bb, acc[0][nt], 0, 0, 0);
      acc[1][nt] = __builtin_amdgcn_mfma_f32_16x16x32_bf16(a1, bb, acc[1][nt], 0, 0, 0);
    }
  }
  #pragma unroll
  for (int mt = 0; mt < 2; ++mt)
    #pragma unroll
    for (int nt = 0; nt < 4; ++nt)
      #pragma unroll
      for (int r = 0; r < 4; ++r) {
        int m = m0 + wm * 32 + mt * 16 + (l >> 4) * 4 + r;   // chunk-local
        int g = n0 + wn * 64 + nt * 16 + lr;                 // global gate col
        int gm = g >> 8, j = g & 255;
        float val = (acc[mt][nt][r] + bias[g - n0]) * gsc;
        xp[((size_t)m * 256 + j) * 4 + gm] = f2bf(val);
      }
}

// ------------------------------------------------------------ K2: recurrence
// 16 blocks x 512 threads, Tc steps. Wave w owns h-cols [32w,32w+32) x 4 gates.
// tau = gamma*2 + half: gate col g = gamma*256 + 32w + half*16 + (lane&15).
__launch_bounds__(512, 2)
__global__ void k2_lstm(const unsigned short* __restrict__ xp,   // chunk base
                        const signed char* __restrict__ Wq,
                        const float* __restrict__ wsc,
                        const signed char* __restrict__ Wlq,
                        const float* __restrict__ lsc,
                        const float* __restrict__ ep,
                        const float* __restrict__ h0,
                        const float* __restrict__ c0,
                        const float* __restrict__ blog,
                        const float* __restrict__ bval,
                        float* __restrict__ hstate,
                        float* __restrict__ cstate,
                        float* __restrict__ out, int t0, int tc, int tcsh) {
  __shared__ signed char Hl[2][16][272];   // h int8, ping-pong, padded rows
  __shared__ signed char Wl[34][272];      // heads weights (32 logit + value + zero)
  __shared__ float flgl[512 * 16];         // [lt][s] episode flags, whole chunk
  const int tid = threadIdx.x;
  const int w = tid >> 6, l = tid & 63;
  const int lc = l & 15, lq = l >> 4;
  const int s0 = (int)blockIdx.x << 4;
  const bool last = (t0 + tc == 512);

  for (int it = 0; it < 5; ++it) {         // stage heads weights
    int idx = it * 512 + tid;
    if (idx < 34 * 64) {
      int row = idx >> 6, c = (idx & 63) << 2;
      int v = (row < 33) ? *(const int*)(Wlq + (size_t)row * 256 + c) : 0;
      *(int*)&Wl[row][c] = v;
    }
  }
  {                                        // stage h (quantized int8)
    const float* hsrc = (t0 == 0) ? h0 : hstate;
    #pragma unroll
    for (int it = 0; it < 8; ++it) {
      int idx = it * 512 + tid;
      int s = idx >> 8, j = idx & 255;
      float v = hsrc[(size_t)(s0 + s) * 256 + j];
      float q = rintf(fminf(fmaxf(v * 127.f, -127.f), 127.f));
      Hl[0][s][j] = (signed char)(int)q;
    }
  }
  {                                        // stage episode flags (coalesced on t)
    int n = tc << 4;
    for (int idx = tid; idx < n; idx += 512) {
      int s = idx >> tcsh, llt = idx & (tc - 1);
      flgl[(llt << 4) + s] = ep[(size_t)(s0 + s) * 512 + t0 + llt];
    }
  }

  i32x4 wq[8][4];                          // persistent int8 W_hh fragments
  float dscP[8];                           // pre-scaled dequant: sgn*L2E*wsc/127
  #pragma unroll
  for (int tau = 0; tau < 8; ++tau) {
    int g = (tau >> 1) * 256 + (w << 5) + ((tau & 1) << 4) + lc;
    #pragma unroll
    for (int kk = 0; kk < 4; ++kk)
      wq[tau][kk] = *(const i32x4*)(Wq + (size_t)g * 256 + kk * 64 + (lq << 4));
    float sgn = ((tau >> 1) == 2) ? L2E2 : -L2E;
    dscP[tau] = sgn * wsc[g] * (1.f / 127.f);
  }
  int lrow; float lb, dls;                 // heads per-lane constants
  if (lc < 4)       { lrow = (w << 2) + lc; lb = blog[lrow]; dls = lsc[lrow] * (1.f / 127.f); }
  else if (lc == 4) { lrow = 32; lb = bval[0]; dls = lsc[32] * (1.f / 127.f); }
  else              { lrow = 33; lb = 0.f; dls = 0.f; }

  float cst[8];                            // c state fp32 (cell = half*4 + r)
  {
    const float* csrc = (t0 == 0) ? c0 : cstate;
    #pragma unroll
    for (int half = 0; half < 2; ++half)
      #pragma unroll
      for (int r = 0; r < 4; ++r)
        cst[half * 4 + r] = csrc[(size_t)(s0 + lq * 4 + r) * 256 + (w << 5) + (half << 4) + lc];
  }

  // xp per-lane elem offset: ((lt*256 + s)*256 + j)*4 + gm ; s=s0+lq*4+r, j=w*32+half*16+lc
  const size_t xoff = ((size_t)(s0 + lq * 4) * 256 + (w << 5) + lc) * 4;
  u16x4 xqA[8], xqB[8];
  {
    const unsigned short* pp = xp + xoff;  // lt = 0
    #pragma unroll
    for (int c = 0; c < 8; ++c)
      xqA[c] = *(const u16x4*)(pp + (c & 3) * 1024 + (c >> 2) * 64);
  }
  __syncthreads();

  i32x4 wlf[4];                            // heads B-fragments (loop-invariant)
  #pragma unroll
  for (int kk = 0; kk < 4; ++kk)
    wlf[kk] = *(const i32x4*)&Wl[lrow][kk * 64 + (lq << 4)];

  const int aoff  = lc * 272 + (lq << 4);            // A-frag lane offset (row=seq)
  const int hwoff = (lq * 4) * 272 + (w << 5) + lc;  // h-write lane offset
  const i32x4 zero4 = {0, 0, 0, 0};

#define STEP(HR, HWR, XC, XN, LT)                                              \
  {                                                                            \
    const int lt_ = (LT);                                                      \
    if (lt_ + 1 < tc) {                  /* early prefetch: next xp -> XN */   \
      const unsigned short* pp = xp + (size_t)(lt_ + 1) * 262144 + xoff;       \
      _Pragma("unroll")                                                        \
      for (int c = 0; c < 8; ++c)                                              \
        XN[c] = *(const u16x4*)(pp + (c & 3) * 1024 + (c >> 2) * 64);          \
    }                                                                          \
    float fa = flgl[(lt_ << 4) + lc];                                          \
    f32x4 frv = *(const f32x4*)&flgl[(lt_ << 4) + (lq << 2)];                  \
    i32x4 racc[8]; i32x4 hacc = zero4;                                         \
    _Pragma("unroll")                                                          \
    for (int tau = 0; tau < 8; ++tau) racc[tau] = zero4;                       \
    const signed char* hbase = (HR);                                           \
    _Pragma("unroll")                                                          \
    for (int kk = 0; kk < 4; ++kk) {                                           \
      i32x4 a = *(const i32x4*)(hbase + aoff + kk * 64);                       \
      hacc = __builtin_amdgcn_mfma_i32_16x16x64_i8(a, wlf[kk], hacc, 0, 0, 0); \
      i32x4 am = (fa != 0.f) ? zero4 : a;                                      \
      _Pragma("unroll")                                                        \
      for (int tau = 0; tau < 8; ++tau)                                        \
        racc[tau] = __builtin_amdgcn_mfma_i32_16x16x64_i8(am, wq[tau][kk], racc[tau], 0, 0, 0); \
    }                                                                          \
    if (lt_ > 0) {                       /* heads for t-1 */                   \
      _Pragma("unroll")                                                        \
      for (int r = 0; r < 4; ++r) {                                            \
        float v = fmaf((float)hacc[r], dls, lb);                               \
        int sg = s0 + lq * 4 + r;                                              \
        if (lc < 4)                                                            \
          out[((size_t)sg * 512 + (t0 + lt_ - 1)) * 32 + lrow] = v;            \
        else if (lc == 4 && w == 0)                                            \
          out[4194304 + (size_t)sg * 512 + (t0 + lt_ - 1)] = v;                \
      }                                                                        \
    }                                                                          \
    signed char* hw = (HWR);                                                   \
    _Pragma("unroll")                                                          \
    for (int half = 0; half < 2; ++half) {                                     \
      _Pragma("unroll")                                                        \
      for (int r = 0; r < 4; ++r) {                                            \
        const int cell = half * 4 + r;                                         \
        u16x4 xv = XC[cell];                                                   \
        float xi = fmaf((float)racc[0 + half][r], dscP[0 + half], bf2f(xv.x)); \
        float xf = fmaf((float)racc[2 + half][r], dscP[2 + half], bf2f(xv.y)); \
        float xg = fmaf((float)racc[4 + half][r], dscP[4 + half], bf2f(xv.z)); \
        float xo = fmaf((float)racc[6 + half][r], dscP[6 + half], bf2f(xv.w)); \
        float si = frcp(1.f + fexp2(xi));                                      \
        float sf = frcp(1.f + fexp2(xf));                                      \
        float so = frcp(1.f + fexp2(xo));                                      \
        float tg = fmaf(-2.f, frcp(1.f + fexp2(xg)), 1.f);                     \
        float cp = (frv[r] != 0.f) ? 0.f : cst[cell];                          \
        float cn = fmaf(sf, cp, si * tg);                                      \
        cst[cell] = cn;                                                        \
        float th = fmaf(-2.f, frcp(1.f + fexp2(L2E2 * cn)), 1.f);              \
        float hn = so * th;                                                    \
        hw[hwoff + r * 272 + (half << 4)] =                                    \
            (signed char)(int)rintf(hn * 127.f);                               \
        if (lt_ == tc - 1) {                                                   \
          int sg = s0 + lq * 4 + r;                                            \
          int j = (w << 5) + (half << 4) + lc;                                 \
          hstate[(size_t)sg * 256 + j] = hn;                                   \
          cstate[(size_t)sg * 256 + j] = cn;                                   \
          if (last) {                                                          \
            out[4325376 + (size_t)sg * 256 + j] = hn;                          \
            out[4390912 + (size_t)sg * 256 + j] = cn;                          \
          }                                                                    \
        }                                                                      \
      }                                                                        \
    }                                                                          \
    __syncthreads();                                                           \
  }

  signed char* H0 = &Hl[0][0][0];
  signed char* H1 = &Hl[1][0][0];
  for (int lt = 0; lt < tc; lt += 2) {     // tc is even (>=32, pow2)
    STEP(H0, H1, xqA, xqB, lt);
    STEP(H1, H0, xqB, xqA, lt + 1);
  }
#undef STEP

  // epilogue: heads for t = t0+tc-1 (even tc => final h in Hl[0])
  {
    i32x4 hacc = zero4;
    #pragma unroll
    for (int kk = 0; kk < 4; ++kk) {
      i32x4 a = *(const i32x4*)(H0 + aoff + kk * 64);
      hacc = __builtin_amdgcn_mfma_i32_16x16x64_i8(a, wlf[kk], hacc, 0, 0, 0);
    }
    #pragma unroll
    for (int r = 0; r < 4; ++r) {
      float v = fmaf((float)hacc[r], dls, lb);
      int sg = s0 + lq * 4 + r;
      if (lc < 4)
        out[((size_t)sg * 512 + (t0 + tc - 1)) * 32 + lrow] = v;
      else if (lc == 4 && w == 0)
        out[4194304 + (size_t)sg * 512 + (t0 + tc - 1)] = v;
    }
  }
}

// ---------------------------------------------------------------- launcher
extern "C" void kernel_launch(void* const* d_in, const int* in_sizes, int n_in,
                              void* d_out, int out_size, void* d_ws, size_t ws_size,
                              hipStream_t stream) {
  const float* feat = (const float*)d_in[0];
  const float* ep   = (const float*)d_in[1];
  const float* h0   = (const float*)d_in[2];
  const float* c0   = (const float*)d_in[3];
  const float* Wih  = (const float*)d_in[4];
  const float* Whh  = (const float*)d_in[5];
  const float* bih  = (const float*)d_in[6];
  const float* bhh  = (const float*)d_in[7];
  const float* Wlog = (const float*)d_in[8];
  const float* blog = (const float*)d_in[9];
  const float* Wval = (const float*)d_in[10];
  const float* bval = (const float*)d_in[11];
  float* out = (float*)d_out;
  char* ws = (char*)d_ws;
  signed char* Wq     = (signed char*)(ws + 0);        // 262144
  float*       wsc    = (float*)      (ws + 262144);   // 4096
  signed char* Wlq    = (signed char*)(ws + 266240);   // 8448
  float*       lsc    = (float*)      (ws + 274688);   // 132
  float*       hstate = (float*)      (ws + 275456);   // 262144
  float*       cstate = (float*)      (ws + 537600);   // 262144 (ends 799744)
  unsigned short* xp  = (unsigned short*)(ws + 1048576);

  int Tc = 512;
  while (Tc > 32 && (size_t)1048576 + (size_t)Tc * 524288 > ws_size) Tc >>= 1;
  int tcsh = 31 - __builtin_clz(Tc);

  hipLaunchKernelGGL(k0_quant, dim3(1057), dim3(64), 0, stream,
                     Whh, Wlog, Wval, Wq, wsc, Wlq, lsc);
  for (int t0 = 0; t0 < 512; t0 += Tc) {
    hipLaunchKernelGGL(k1_inproj, dim3(Tc * 32), dim3(256), 0, stream,
                       feat, Wih, bih, bhh, xp, t0);
    hipLaunchKernelGGL(k2_lstm, dim3(16), dim3(512), 0, stream,
                       xp, Wq, wsc, Wlq, lsc, ep, h0, c0, blog, bval,
                       hstate, cstate, out, t0, Tc, tcsh);
  }
}

// Round 4
// 1375.614 us; speedup vs baseline: 1.6108x; 1.5311x over previous
//
#include <hip/hip_runtime.h>
#include <hip/hip_bf16.h>

// ACLSTM on MI355X — persistent-RNN design, time-chunked to fit ws_size.
// R4: (1) no-drain barrier in K2 (s_waitcnt lgkmcnt(0)+s_barrier only; xq HBM
//     prefetch loads stay in flight across steps, head/global stores never
//     drained per-step); (2) heads stripped out of the serial loop into K3
//     (parallel int8 GEMM over hbuf written coalesced by K2).

typedef float f32x4 __attribute__((ext_vector_type(4)));
typedef int   i32x4 __attribute__((ext_vector_type(4)));
typedef short s16x8 __attribute__((ext_vector_type(8)));
typedef short s16x4 __attribute__((ext_vector_type(4)));
typedef unsigned short u16x4 __attribute__((ext_vector_type(4)));

#define L2E  1.44269504088896340736f
#define L2E2 2.88539008177792681472f

__device__ __forceinline__ float fexp2(float x) {
#if __has_builtin(__builtin_amdgcn_exp2f)
  return __builtin_amdgcn_exp2f(x);
#else
  float r; asm("v_exp_f32 %0, %1" : "=v"(r) : "v"(x)); return r;
#endif
}
__device__ __forceinline__ float frcp(float x) { return __builtin_amdgcn_rcpf(x); }
__device__ __forceinline__ float bf2f(unsigned short u) {
  return __uint_as_float(((unsigned)u) << 16);
}
__device__ __forceinline__ unsigned short f2bf(float f) {   // RNE f32->bf16
  unsigned int b = __float_as_uint(f);
  return (unsigned short)((b + 0x7FFFu + ((b >> 16) & 1u)) >> 16);
}

// ---------------------------------------------------------------- K0: quant
__global__ void k0_quant(const float* __restrict__ Whh,
                         const float* __restrict__ Wlog,
                         const float* __restrict__ Wval,
                         signed char* __restrict__ Wq, float* __restrict__ wsc,
                         signed char* __restrict__ Wlq, float* __restrict__ lsc) {
  int r = blockIdx.x, l = threadIdx.x;   // 1057 rows, 64 lanes
  const float* src; signed char* dst; float* sd;
  if (r < 1024) { src = Whh + (size_t)r * 256; dst = Wq + (size_t)r * 256; sd = wsc + r; }
  else {
    int hr = r - 1024;
    src = (hr < 32) ? (Wlog + (size_t)hr * 256) : Wval;
    dst = Wlq + (size_t)hr * 256; sd = lsc + hr;
  }
  f32x4 v = *(const f32x4*)(src + l * 4);
  float m = fmaxf(fmaxf(fabsf(v.x), fabsf(v.y)), fmaxf(fabsf(v.z), fabsf(v.w)));
  #pragma unroll
  for (int off = 32; off; off >>= 1) m = fmaxf(m, __shfl_xor(m, off));
  float inv = (m > 0.f) ? (127.f / m) : 0.f;
  int q0 = (int)rintf(v.x * inv), q1 = (int)rintf(v.y * inv);
  int q2 = (int)rintf(v.z * inv), q3 = (int)rintf(v.w * inv);
  unsigned int pk = (q0 & 255) | ((q1 & 255) << 8) | ((q2 & 255) << 16) | ((q3 & 255) << 24);
  *(unsigned int*)(dst + l * 4) = pk;
  if (l == 0) *sd = m * (1.f / 127.f);
}

// ------------------------------------------------------------- K1: x_proj
// Chunk-local m = lt*256+s. Output: xp[(m*256+j)*4+gm], gate col g = gm*256+j.
// Stored PRE-SCALED: (x+b)*(-L2E) for gm in {0,1,3}, (x+b)*L2E2 for gm==2.
__launch_bounds__(256)
__global__ void k1_inproj(const float* __restrict__ feat,
                          const float* __restrict__ Wih,
                          const float* __restrict__ bih,
                          const float* __restrict__ bhh,
                          unsigned short* __restrict__ xp, int t0) {
  __shared__ short Al[64][136];
  __shared__ short Bl[128][136];
  __shared__ float bias[128];
  int tid = threadIdx.x;
  int bm = blockIdx.x >> 3, bn = blockIdx.x & 7;
  int m0 = bm << 6, n0 = bn << 7;
  int tg = t0 + (m0 >> 8), sbase = m0 & 255;   // 64 | 256 => single t per tile
  const float gsc = ((n0 >> 8) == 2) ? L2E2 : -L2E;
  #pragma unroll
  for (int it = 0; it < 8; ++it) {             // A: 64x128 f32 -> bf16
    int idx = it * 256 + tid;
    int row = idx >> 5, c4 = (idx & 31) << 2;
    f32x4 v = *(const f32x4*)(feat + ((size_t)(sbase + row) * 512 + tg) * 128 + c4);
    s16x4 pk = { (short)f2bf(v.x), (short)f2bf(v.y), (short)f2bf(v.z), (short)f2bf(v.w) };
    *(s16x4*)&Al[row][c4] = pk;
  }
  #pragma unroll
  for (int it = 0; it < 16; ++it) {            // B: 128x128 (W_ih rows = gate cols)
    int idx = it * 256 + tid;
    int row = idx >> 5, c4 = (idx & 31) << 2;
    f32x4 v = *(const f32x4*)(Wih + (size_t)(n0 + row) * 128 + c4);
    s16x4 pk = { (short)f2bf(v.x), (short)f2bf(v.y), (short)f2bf(v.z), (short)f2bf(v.w) };
    *(s16x4*)&Bl[row][c4] = pk;
  }
  if (tid < 128) bias[tid] = bih[n0 + tid] + bhh[n0 + tid];
  __syncthreads();
  int w = tid >> 6, l = tid & 63;
  int wm = w >> 1, wn = w & 1;                 // 2x2 wave grid: 32m x 64n per wave
  int lr = l & 15, lk = (l >> 4) << 3;
  f32x4 z = {0.f, 0.f, 0.f, 0.f};
  f32x4 acc[2][4];
  #pragma unroll
  for (int mt = 0; mt < 2; ++mt)
    #pragma unroll
    for (int nt = 0; nt < 4; ++nt) acc[mt][nt] = z;
  #pragma unroll
  for (int kk = 0; kk < 4; ++kk) {
    s16x8 a0 = *(const s16x8*)&Al[wm * 32 + lr][kk * 32 + lk];
    s16x8 a1 = *(const s16x8*)&Al[wm * 32 + 16 + lr][kk * 32 + lk];
    #pragma unroll
    for (int nt = 0; nt < 4; ++nt) {
      s16x8 bb = *(const s16x8*)&Bl[wn * 64 + nt * 16 + lr][kk * 32 + lk];
      acc[0][nt] = __builtin_amdgcn_mfma_f32_16x16x32_bf16(a0, bb, acc[0][nt], 0, 0, 0);
      acc[1][nt] = __builtin_amdgcn_mfma_f32_16x16x32_bf16(a1, bb, acc[1][nt], 0, 0, 0);
    }
  }
  #pragma unroll
  for (int mt = 0; mt < 2; ++mt)
    #pragma unroll
    for (int nt = 0; nt < 4; ++nt)
      #pragma unroll
      for (int r = 0; r < 4; ++r) {
        int m = m0 + wm * 32 + mt * 16 + (l >> 4) * 4 + r;   // chunk-local
        int g = n0 + wn * 64 + nt * 16 + lr;                 // global gate col
        int gm = g >> 8, j = g & 255;
        float val = (acc[mt][nt][r] + bias[g - n0]) * gsc;
        xp[((size_t)m * 256 + j) * 4 + gm] = f2bf(val);
      }
}

// ------------------------------------------------------------ K2: recurrence
// 16 blocks x 512 threads, Tc steps. Wave w owns h-cols [32w,32w+32) x 4 gates.
// No-drain barrier: only lgkmcnt(0) before s_barrier; xq loads drain at use.
__launch_bounds__(512, 2)
__global__ void k2_lstm(const unsigned short* __restrict__ xp,   // chunk base
                        const signed char* __restrict__ Wq,
                        const float* __restrict__ wsc,
                        const float* __restrict__ ep,
                        const float* __restrict__ h0,
                        const float* __restrict__ c0,
                        float* __restrict__ hstate,
                        float* __restrict__ cstate,
                        signed char* __restrict__ hbuf,
                        float* __restrict__ out, int t0, int tc, int tcsh) {
  __shared__ signed char Hl[2][16][272];   // h int8, ping-pong, padded rows
  __shared__ float flgl[512 * 16];         // [lt][s] episode flags, whole chunk
  const int tid = threadIdx.x;
  const int w = tid >> 6, l = tid & 63;
  const int lc = l & 15, lq = l >> 4;
  const int s0 = (int)blockIdx.x << 4;
  const bool last = (t0 + tc == 512);

  {                                        // stage h (quantized int8)
    const float* hsrc = (t0 == 0) ? h0 : hstate;
    #pragma unroll
    for (int it = 0; it < 8; ++it) {
      int idx = it * 512 + tid;
      int s = idx >> 8, j = idx & 255;
      float v = hsrc[(size_t)(s0 + s) * 256 + j];
      float q = rintf(fminf(fmaxf(v * 127.f, -127.f), 127.f));
      Hl[0][s][j] = (signed char)(int)q;
    }
  }
  {                                        // stage episode flags (coalesced on t)
    int n = tc << 4;
    for (int idx = tid; idx < n; idx += 512) {
      int s = idx >> tcsh, llt = idx & (tc - 1);
      flgl[(llt << 4) + s] = ep[(size_t)(s0 + s) * 512 + t0 + llt];
    }
  }

  i32x4 wq[8][4];                          // persistent int8 W_hh fragments
  float dscP[8];                           // pre-scaled dequant
  #pragma unroll
  for (int tau = 0; tau < 8; ++tau) {
    int g = (tau >> 1) * 256 + (w << 5) + ((tau & 1) << 4) + lc;
    #pragma unroll
    for (int kk = 0; kk < 4; ++kk)
      wq[tau][kk] = *(const i32x4*)(Wq + (size_t)g * 256 + kk * 64 + (lq << 4));
    float sgn = ((tau >> 1) == 2) ? L2E2 : -L2E;
    dscP[tau] = sgn * wsc[g] * (1.f / 127.f);
  }

  float cst[8];                            // c state fp32 (cell = half*4 + r)
  {
    const float* csrc = (t0 == 0) ? c0 : cstate;
    #pragma unroll
    for (int half = 0; half < 2; ++half)
      #pragma unroll
      for (int r = 0; r < 4; ++r)
        cst[half * 4 + r] = csrc[(size_t)(s0 + lq * 4 + r) * 256 + (w << 5) + (half << 4) + lc];
  }

  // xp per-lane elem offset: ((lt*256 + s)*256 + j)*4 + gm
  const size_t xoff = ((size_t)(s0 + lq * 4) * 256 + (w << 5) + lc) * 4;
  u16x4 xqA[8], xqB[8];
  {
    const unsigned short* pp = xp + xoff;  // lt = 0
    #pragma unroll
    for (int c = 0; c < 8; ++c)
      xqA[c] = *(const u16x4*)(pp + (c & 3) * 1024 + (c >> 2) * 64);
  }
  __syncthreads();                          // full barrier once (staging)

  const int aoff  = lc * 272 + (lq << 4);            // A-frag lane offset (row=seq)
  const int hwoff = (lq * 4) * 272 + (w << 5) + lc;  // h-write lane offset (LDS)
  const int hboff = (lq * 4) * 256 + (w << 5) + lc;  // h-write lane offset (hbuf)
  const size_t bq = (size_t)blockIdx.x * tc;
  const i32x4 zero4 = {0, 0, 0, 0};

#define STEP(HR, HWR, XC, XN, LT)                                              \
  {                                                                            \
    const int lt_ = (LT);                                                      \
    if (lt_ + 1 < tc) {                  /* early prefetch: next xp -> XN */   \
      const unsigned short* pp = xp + (size_t)(lt_ + 1) * 262144 + xoff;       \
      _Pragma("unroll")                                                        \
      for (int c = 0; c < 8; ++c)                                              \
        XN[c] = *(const u16x4*)(pp + (c & 3) * 1024 + (c >> 2) * 64);          \
    }                                                                          \
    float fa = flgl[(lt_ << 4) + lc];                                          \
    f32x4 frv = *(const f32x4*)&flgl[(lt_ << 4) + (lq << 2)];                  \
    i32x4 racc[8];                                                             \
    _Pragma("unroll")                                                          \
    for (int tau = 0; tau < 8; ++tau) racc[tau] = zero4;                       \
    const signed char* hbase = (HR);                                           \
    _Pragma("unroll")                                                          \
    for (int kk = 0; kk < 4; ++kk) {                                           \
      i32x4 a = *(const i32x4*)(hbase + aoff + kk * 64);                       \
      i32x4 am = (fa != 0.f) ? zero4 : a;                                      \
      _Pragma("unroll")                                                        \
      for (int tau = 0; tau < 8; ++tau)                                        \
        racc[tau] = __builtin_amdgcn_mfma_i32_16x16x64_i8(am, wq[tau][kk], racc[tau], 0, 0, 0); \
    }                                                                          \
    signed char* hw = (HWR);                                                   \
    signed char* hb = hbuf + ((bq + lt_) << 12) + hboff;                       \
    _Pragma("unroll")                                                          \
    for (int half = 0; half < 2; ++half) {                                     \
      _Pragma("unroll")                                                        \
      for (int r = 0; r < 4; ++r) {                                            \
        const int cell = half * 4 + r;                                         \
        u16x4 xv = XC[cell];                                                   \
        float xi = fmaf((float)racc[0 + half][r], dscP[0 + half], bf2f(xv.x)); \
        float xf = fmaf((float)racc[2 + half][r], dscP[2 + half], bf2f(xv.y)); \
        float xg = fmaf((float)racc[4 + half][r], dscP[4 + half], bf2f(xv.z)); \
        float xo = fmaf((float)racc[6 + half][r], dscP[6 + half], bf2f(xv.w)); \
        float si = frcp(1.f + fexp2(xi));                                      \
        float sf = frcp(1.f + fexp2(xf));                                      \
        float so = frcp(1.f + fexp2(xo));                                      \
        float tg = fmaf(-2.f, frcp(1.f + fexp2(xg)), 1.f);                     \
        float cp = (frv[r] != 0.f) ? 0.f : cst[cell];                          \
        float cn = fmaf(sf, cp, si * tg);                                      \
        cst[cell] = cn;                                                        \
        float th = fmaf(-2.f, frcp(1.f + fexp2(L2E2 * cn)), 1.f);              \
        float hn = so * th;                                                    \
        signed char q8 = (signed char)(int)rintf(hn * 127.f);                  \
        hw[hwoff + r * 272 + (half << 4)] = q8;                                \
        hb[r * 256 + (half << 4)] = q8;                                        \
        if (lt_ == tc - 1) {                                                   \
          int sg = s0 + lq * 4 + r;                                            \
          int j = (w << 5) + (half << 4) + lc;                                 \
          hstate[(size_t)sg * 256 + j] = hn;                                   \
          cstate[(size_t)sg * 256 + j] = cn;                                   \
          if (last) {                                                          \
            out[4325376 + (size_t)sg * 256 + j] = hn;                          \
            out[4390912 + (size_t)sg * 256 + j] = cn;                          \
          }                                                                    \
        }                                                                      \
      }                                                                        \
    }                                                                          \
    asm volatile("s_waitcnt lgkmcnt(0)\n\ts_barrier" ::: "memory");            \
  }

  signed char* H0 = &Hl[0][0][0];
  signed char* H1 = &Hl[1][0][0];
  for (int lt = 0; lt < tc; lt += 2) {     // tc is even (>=32, pow2)
    STEP(H0, H1, xqA, xqB, lt);
    STEP(H1, H0, xqB, xqA, lt + 1);
  }
#undef STEP
}

// ------------------------------------------------------------ K3: heads GEMM
// logits/value from int8 hbuf. One wave per (b,lt): 16 seqs x 48 head cols.
__launch_bounds__(256)
__global__ void k3_heads(const signed char* __restrict__ hbuf,
                         const signed char* __restrict__ Wlq,
                         const float* __restrict__ lsc,
                         const float* __restrict__ blog,
                         const float* __restrict__ bval,
                         float* __restrict__ out, int t0, int tc, int tcsh) {
  const int w = threadIdx.x >> 6, l = threadIdx.x & 63;
  const int lc = l & 15, lq = l >> 4;
  const int bt = (int)blockIdx.x * 4 + w;       // 0 .. 16*tc-1
  const int b = bt >> tcsh, lt = bt & (tc - 1);
  const int t = t0 + lt;
  const i32x4 zero4 = {0, 0, 0, 0};

  i32x4 dacc[3] = {zero4, zero4, zero4};
  #pragma unroll
  for (int kk = 0; kk < 4; ++kk) {
    i32x4 a = *(const i32x4*)(hbuf + (((size_t)bt << 4) + lc) * 256 + kk * 64 + (lq << 4));
    #pragma unroll
    for (int n = 0; n < 3; ++n) {
      int row = n * 16 + lc;
      i32x4 bf = (row < 33) ? *(const i32x4*)(Wlq + (size_t)row * 256 + kk * 64 + (lq << 4))
                            : zero4;
      dacc[n] = __builtin_amdgcn_mfma_i32_16x16x64_i8(a, bf, dacc[n], 0, 0, 0);
    }
  }
  #pragma unroll
  for (int n = 0; n < 2; ++n) {
    float dsn = lsc[n * 16 + lc] * (1.f / 127.f);
    float lbn = blog[n * 16 + lc];
    #pragma unroll
    for (int r = 0; r < 4; ++r) {
      int sg = (b << 4) + lq * 4 + r;
      out[((size_t)sg * 512 + t) * 32 + n * 16 + lc] = fmaf((float)dacc[n][r], dsn, lbn);
    }
  }
  if (lc == 0) {
    float ds2 = lsc[32] * (1.f / 127.f);
    float b2 = bval[0];
    #pragma unroll
    for (int r = 0; r < 4; ++r) {
      int sg = (b << 4) + lq * 4 + r;
      out[4194304 + (size_t)sg * 512 + t] = fmaf((float)dacc[2][r], ds2, b2);
    }
  }
}

// ---------------------------------------------------------------- launcher
extern "C" void kernel_launch(void* const* d_in, const int* in_sizes, int n_in,
                              void* d_out, int out_size, void* d_ws, size_t ws_size,
                              hipStream_t stream) {
  const float* feat = (const float*)d_in[0];
  const float* ep   = (const float*)d_in[1];
  const float* h0   = (const float*)d_in[2];
  const float* c0   = (const float*)d_in[3];
  const float* Wih  = (const float*)d_in[4];
  const float* Whh  = (const float*)d_in[5];
  const float* bih  = (const float*)d_in[6];
  const float* bhh  = (const float*)d_in[7];
  const float* Wlog = (const float*)d_in[8];
  const float* blog = (const float*)d_in[9];
  const float* Wval = (const float*)d_in[10];
  const float* bval = (const float*)d_in[11];
  float* out = (float*)d_out;
  char* ws = (char*)d_ws;
  signed char* Wq     = (signed char*)(ws + 0);        // 262144
  float*       wsc    = (float*)      (ws + 262144);   // 4096
  signed char* Wlq    = (signed char*)(ws + 266240);   // 8448
  float*       lsc    = (float*)      (ws + 274688);   // 132
  float*       hstate = (float*)      (ws + 275456);   // 262144
  float*       cstate = (float*)      (ws + 537600);   // 262144 (ends 799744)
  unsigned short* xp  = (unsigned short*)(ws + 1048576);

  // 1 MiB + Tc*(512 KiB xp + 64 KiB hbuf) <= ws_size
  int Tc = 512;
  while (Tc > 32 && (size_t)1048576 + (size_t)Tc * 589824 > ws_size) Tc >>= 1;
  int tcsh = 31 - __builtin_clz(Tc);
  signed char* hbuf = (signed char*)(ws + 1048576 + (size_t)Tc * 524288);

  hipLaunchKernelGGL(k0_quant, dim3(1057), dim3(64), 0, stream,
                     Whh, Wlog, Wval, Wq, wsc, Wlq, lsc);
  for (int t0 = 0; t0 < 512; t0 += Tc) {
    hipLaunchKernelGGL(k1_inproj, dim3(Tc * 32), dim3(256), 0, stream,
                       feat, Wih, bih, bhh, xp, t0);
    hipLaunchKernelGGL(k2_lstm, dim3(16), dim3(512), 0, stream,
                       xp, Wq, wsc, ep, h0, c0, hstate, cstate, hbuf, out, t0, Tc, tcsh);
    hipLaunchKernelGGL(k3_heads, dim3(Tc * 4), dim3(256), 0, stream,
                       hbuf, Wlq, lsc, blog, bval, out, t0, Tc, tcsh);
  }
}

// Round 6
// 862.305 us; speedup vs baseline: 2.5696x; 1.5953x over previous
//
#include <hip/hip_runtime.h>
#include <hip/hip_bf16.h>

// ACLSTM on MI355X — persistent-RNN, time-chunked + software-pipelined.
// R6: bisection round. Keep: mega pipeline (k2 j | k1 j+1 | k3 j-1), 32 k2
//     blocks x 8 seqs. Revert/replace risky R5 micro-changes:
//     - NO shfl: h rows duplicated in LDS (s and s+8) so every lane's own
//       racc[gamma*2+hf] holds its 4 valid cells (constant indices only).
//     - mask-at-read (R4-proven cndmask), unmasked staging/writes.
//     - rintf quantization (magic-FMA reverted).
//     - k1 = R4's exact 256-thread body under tid<256 guards.

typedef float f32x4 __attribute__((ext_vector_type(4)));
typedef int   i32x4 __attribute__((ext_vector_type(4)));
typedef short s16x8 __attribute__((ext_vector_type(8)));
typedef short s16x4 __attribute__((ext_vector_type(4)));
typedef unsigned short u16x4 __attribute__((ext_vector_type(4)));

#define L2E   1.44269504088896340736f
#define L2E2  2.88539008177792681472f

__device__ __forceinline__ float fexp2(float x) {
#if __has_builtin(__builtin_amdgcn_exp2f)
  return __builtin_amdgcn_exp2f(x);
#else
  float r; asm("v_exp_f32 %0, %1" : "=v"(r) : "v"(x)); return r;
#endif
}
__device__ __forceinline__ float frcp(float x) { return __builtin_amdgcn_rcpf(x); }
__device__ __forceinline__ float bf2f(unsigned short u) {
  return __uint_as_float(((unsigned)u) << 16);
}
__device__ __forceinline__ unsigned short f2bf(float f) {   // RNE f32->bf16
  unsigned int b = __float_as_uint(f);
  return (unsigned short)((b + 0x7FFFu + ((b >> 16) & 1u)) >> 16);
}

// ---------------------------------------------------------------- K0: quant
__global__ void k0_quant(const float* __restrict__ Whh,
                         const float* __restrict__ Wlog,
                         const float* __restrict__ Wval,
                         signed char* __restrict__ Wq, float* __restrict__ wsc,
                         signed char* __restrict__ Wlq, float* __restrict__ lsc) {
  int r = blockIdx.x, l = threadIdx.x;   // 1057 rows, 64 lanes
  const float* src; signed char* dst; float* sd;
  if (r < 1024) { src = Whh + (size_t)r * 256; dst = Wq + (size_t)r * 256; sd = wsc + r; }
  else {
    int hr = r - 1024;
    src = (hr < 32) ? (Wlog + (size_t)hr * 256) : Wval;
    dst = Wlq + (size_t)hr * 256; sd = lsc + hr;
  }
  f32x4 v = *(const f32x4*)(src + l * 4);
  float m = fmaxf(fmaxf(fabsf(v.x), fabsf(v.y)), fmaxf(fabsf(v.z), fabsf(v.w)));
  #pragma unroll
  for (int off = 32; off; off >>= 1) m = fmaxf(m, __shfl_xor(m, off));
  float inv = (m > 0.f) ? (127.f / m) : 0.f;
  int q0 = (int)rintf(v.x * inv), q1 = (int)rintf(v.y * inv);
  int q2 = (int)rintf(v.z * inv), q3 = (int)rintf(v.w * inv);
  unsigned int pk = (q0 & 255) | ((q1 & 255) << 8) | ((q2 & 255) << 16) | ((q3 & 255) << 24);
  *(unsigned int*)(dst + l * 4) = pk;
  if (l == 0) *sd = m * (1.f / 127.f);
}

// ================================================================ bodies
// --- K1 body: R4's exact 256-thread tile (64m x 128n), 512-thread wrapper.
__device__ __forceinline__ void k1_body(int gk, char* smem,
                                        const float* __restrict__ feat,
                                        const float* __restrict__ Wih,
                                        const float* __restrict__ bih,
                                        const float* __restrict__ bhh,
                                        unsigned short* __restrict__ xp, int t0) {
  short (*Al)[136] = (short (*)[136])smem;                  // 17408 B
  short (*Bl)[136] = (short (*)[136])(smem + 17408);        // 34816 B
  float* bias = (float*)(smem + 17408 + 34816);             // 512 B
  int tid = threadIdx.x;
  int bm = gk >> 3, bn = gk & 7;
  int m0 = bm << 6, n0 = bn << 7;
  int tg = t0 + (m0 >> 8), sbase = m0 & 255;   // 64 | 256 => single t per tile
  const float gsc = ((n0 >> 8) == 2) ? L2E2 : -L2E;
  if (tid < 256) {
    #pragma unroll
    for (int it = 0; it < 8; ++it) {             // A: 64x128 f32 -> bf16
      int idx = it * 256 + tid;
      int row = idx >> 5, c4 = (idx & 31) << 2;
      f32x4 v = *(const f32x4*)(feat + ((size_t)(sbase + row) * 512 + tg) * 128 + c4);
      s16x4 pk = { (short)f2bf(v.x), (short)f2bf(v.y), (short)f2bf(v.z), (short)f2bf(v.w) };
      *(s16x4*)&Al[row][c4] = pk;
    }
    #pragma unroll
    for (int it = 0; it < 16; ++it) {            // B: 128x128 (W_ih rows = gate cols)
      int idx = it * 256 + tid;
      int row = idx >> 5, c4 = (idx & 31) << 2;
      f32x4 v = *(const f32x4*)(Wih + (size_t)(n0 + row) * 128 + c4);
      s16x4 pk = { (short)f2bf(v.x), (short)f2bf(v.y), (short)f2bf(v.z), (short)f2bf(v.w) };
      *(s16x4*)&Bl[row][c4] = pk;
    }
    if (tid < 128) bias[tid] = bih[n0 + tid] + bhh[n0 + tid];
  }
  __syncthreads();
  if (tid >= 256) return;
  int w = tid >> 6, l = tid & 63;
  int wm = w >> 1, wn = w & 1;                 // 2x2 wave grid: 32m x 64n per wave
  int lr = l & 15, lk = (l >> 4) << 3;
  f32x4 z = {0.f, 0.f, 0.f, 0.f};
  f32x4 acc[2][4];
  #pragma unroll
  for (int mt = 0; mt < 2; ++mt)
    #pragma unroll
    for (int nt = 0; nt < 4; ++nt) acc[mt][nt] = z;
  #pragma unroll
  for (int kk = 0; kk < 4; ++kk) {
    s16x8 a0 = *(const s16x8*)&Al[wm * 32 + lr][kk * 32 + lk];
    s16x8 a1 = *(const s16x8*)&Al[wm * 32 + 16 + lr][kk * 32 + lk];
    #pragma unroll
    for (int nt = 0; nt < 4; ++nt) {
      s16x8 bb = *(const s16x8*)&Bl[wn * 64 + nt * 16 + lr][kk * 32 + lk];
      acc[0][nt] = __builtin_amdgcn_mfma_f32_16x16x32_bf16(a0, bb, acc[0][nt], 0, 0, 0);
      acc[1][nt] = __builtin_amdgcn_mfma_f32_16x16x32_bf16(a1, bb, acc[1][nt], 0, 0, 0);
    }
  }
  #pragma unroll
  for (int mt = 0; mt < 2; ++mt)
    #pragma unroll
    for (int nt = 0; nt < 4; ++nt)
      #pragma unroll
      for (int r = 0; r < 4; ++r) {
        int m = m0 + wm * 32 + mt * 16 + (l >> 4) * 4 + r;   // chunk-local
        int g = n0 + wn * 64 + nt * 16 + lr;                 // global gate col
        int gm = g >> 8, j = g & 255;
        float val = (acc[mt][nt][r] + bias[g - n0]) * gsc;
        xp[((size_t)m * 256 + j) * 4 + gm] = f2bf(val);
      }
}

// --- K2 body: 32 blocks x 8 seqs, tc steps, duplicated h rows (s and s+8).
__device__ __forceinline__ void k2_body(int bid, char* smem,
                                        const unsigned short* __restrict__ xp,
                                        const signed char* __restrict__ Wq,
                                        const float* __restrict__ wsc,
                                        const float* __restrict__ ep,
                                        const float* __restrict__ h0,
                                        const float* __restrict__ c0,
                                        float* __restrict__ hstate,
                                        float* __restrict__ cstate,
                                        signed char* __restrict__ hbuf,
                                        float* __restrict__ out, int t0, int tc) {
  __builtin_amdgcn_s_setprio(3);           // recurrence is the critical path
  signed char (*Hl)[16][272] = (signed char (*)[16][272])smem;  // 2x16x272=8704
  float* flgl = (float*)(smem + 8704);     // [lt][8] flags, tc*32 B
  const int tid = threadIdx.x;
  const int w = tid >> 6, l = tid & 63;
  const int lc = l & 15, lq = l >> 4;
  const int hf = lq >> 1;                  // which 16-col half of the wave's 32
  const int sb = (lq & 1) << 2;            // lane's seq base (0 or 4)
  const int j = (w << 5) + (hf << 4) + lc; // lane's h-column
  const int s0 = bid << 3;
  const bool last = (t0 + tc == 512);

  {                                        // stage h rows 0..15 (dup, unmasked)
    const float* hsrc = (t0 == 0) ? h0 : hstate;
    #pragma unroll
    for (int it = 0; it < 8; ++it) {
      int idx = it * 512 + tid;            // 0..4095
      int srow = idx >> 8, jj = idx & 255;
      float v = hsrc[(size_t)(s0 + (srow & 7)) * 256 + jj];
      float q = rintf(fminf(fmaxf(v * 127.f, -127.f), 127.f));
      Hl[0][srow][jj] = (signed char)(int)q;
    }
  }
  {                                        // stage episode flags [lt][8]
    int n = tc << 3;
    for (int idx = tid; idx < n; idx += 512) {
      int s = idx & 7, llt = idx >> 3;
      flgl[idx] = ep[(size_t)(s0 + s) * 512 + t0 + llt];
    }
  }

  i32x4 wq[8][4];                          // persistent int8 W_hh fragments
  #pragma unroll
  for (int tau = 0; tau < 8; ++tau) {
    int g = (tau >> 1) * 256 + (w << 5) + ((tau & 1) << 4) + lc;
    #pragma unroll
    for (int kk = 0; kk < 4; ++kk)
      wq[tau][kk] = *(const i32x4*)(Wq + (size_t)g * 256 + kk * 64 + (lq << 4));
  }
  float dsc[4];                            // consumer-lane dequant scales
  #pragma unroll
  for (int gamma = 0; gamma < 4; ++gamma) {
    float sgn = (gamma == 2) ? L2E2 : -L2E;
    dsc[gamma] = sgn * wsc[gamma * 256 + j] * (1.f / 127.f);
  }

  float cst[4];                            // c state fp32, seqs sb+0..3, col j
  {
    const float* csrc = (t0 == 0) ? c0 : cstate;
    #pragma unroll
    for (int r = 0; r < 4; ++r)
      cst[r] = csrc[(size_t)(s0 + sb + r) * 256 + j];
  }

  // xp per-lane elem offset: ((lt*256 + s)*256 + j)*4 ; s = s0+sb+r
  const size_t xoff = ((size_t)(s0 + sb) * 256 + j) * 4;
  u16x4 xqA[4], xqB[4];
  {
    const unsigned short* pp = xp + xoff;  // lt = 0
    #pragma unroll
    for (int r = 0; r < 4; ++r) xqA[r] = *(const u16x4*)(pp + r * 1024);
  }
  __syncthreads();                          // staging barrier (full, once)

  const int aoff  = lc * 272 + (lq << 4);  // A-frag lane offset (row: seq lc&7)
  const int hwoff = sb * 272 + j;          // h-write lane offset (LDS)
  const i32x4 zero4 = {0, 0, 0, 0};

#define STEP(HR, HWR, XC, XN, LT)                                              \
  {                                                                            \
    const int lt_ = (LT);                                                      \
    if (lt_ + 1 < tc) {                  /* early prefetch: next xp -> XN */   \
      const unsigned short* pp = xp + (size_t)(lt_ + 1) * 262144 + xoff;       \
      _Pragma("unroll")                                                        \
      for (int r = 0; r < 4; ++r) XN[r] = *(const u16x4*)(pp + r * 1024);      \
    }                                                                          \
    float fa = flgl[lt_ * 8 + (lc & 7)];   /* reset flag, A-row's seq */       \
    f32x4 frv = *(const f32x4*)&flgl[lt_ * 8 + sb];                            \
    i32x4 racc[8];                                                             \
    const signed char* hbase = &(HR)[0][0];                                    \
    {                                                                          \
      i32x4 a = *(const i32x4*)(hbase + aoff);                                 \
      i32x4 am = (fa != 0.f) ? zero4 : a;                                      \
      _Pragma("unroll")                                                        \
      for (int tau = 0; tau < 8; ++tau)                                        \
        racc[tau] = __builtin_amdgcn_mfma_i32_16x16x64_i8(am, wq[tau][0], zero4, 0, 0, 0); \
    }                                                                          \
    _Pragma("unroll")                                                          \
    for (int kk = 1; kk < 4; ++kk) {                                           \
      i32x4 a = *(const i32x4*)(hbase + aoff + kk * 64);                       \
      i32x4 am = (fa != 0.f) ? zero4 : a;                                      \
      _Pragma("unroll")                                                        \
      for (int tau = 0; tau < 8; ++tau)                                        \
        racc[tau] = __builtin_amdgcn_mfma_i32_16x16x64_i8(am, wq[tau][kk], racc[tau], 0, 0, 0); \
    }                                                                          \
    signed char* hw = &(HWR)[0][0];                                            \
    signed char* hb = hbuf + ((size_t)(bid * tc + lt_) * 8 + sb) * 256 + j;    \
    _Pragma("unroll")                                                          \
    for (int r = 0; r < 4; ++r) {                                              \
      int g0 = hf ? racc[1][r] : racc[0][r];   /* constant indices + select */ \
      int g1 = hf ? racc[3][r] : racc[2][r];                                   \
      int g2 = hf ? racc[5][r] : racc[4][r];                                   \
      int g3 = hf ? racc[7][r] : racc[6][r];                                   \
      u16x4 xv = XC[r];                                                        \
      float xi = fmaf((float)g0, dsc[0], bf2f(xv.x));                          \
      float xf = fmaf((float)g1, dsc[1], bf2f(xv.y));                          \
      float xg = fmaf((float)g2, dsc[2], bf2f(xv.z));                          \
      float xo = fmaf((float)g3, dsc[3], bf2f(xv.w));                          \
      float si = frcp(1.f + fexp2(xi));                                        \
      float sf = frcp(1.f + fexp2(xf));                                        \
      float so = frcp(1.f + fexp2(xo));                                        \
      float tg = fmaf(-2.f, frcp(1.f + fexp2(xg)), 1.f);                       \
      float cp = (frv[r] != 0.f) ? 0.f : cst[r];                               \
      float cn = fmaf(sf, cp, si * tg);                                        \
      cst[r] = cn;                                                             \
      float th = fmaf(-2.f, frcp(1.f + fexp2(L2E2 * cn)), 1.f);                \
      float hn = so * th;                                                      \
      signed char q8 = (signed char)(int)rintf(hn * 127.f);                    \
      hw[hwoff + r * 272] = q8;            /* row sb+r   */                    \
      hw[hwoff + r * 272 + 2176] = q8;     /* row sb+r+8 (dup) */              \
      hb[r * 256] = q8;                                                        \
      if (lt_ == tc - 1) {                                                     \
        int sg = s0 + sb + r;                                                  \
        hstate[(size_t)sg * 256 + j] = hn;                                     \
        cstate[(size_t)sg * 256 + j] = cn;                                     \
        if (last) {                                                            \
          out[4325376 + (size_t)sg * 256 + j] = hn;                            \
          out[4390912 + (size_t)sg * 256 + j] = cn;                            \
        }                                                                      \
      }                                                                        \
    }                                                                          \
    asm volatile("s_waitcnt lgkmcnt(0)\n\ts_barrier" ::: "memory");            \
  }

  for (int lt = 0; lt < tc; lt += 2) {     // tc even
    STEP(Hl[0], Hl[1], xqA, xqB, lt);
    STEP(Hl[1], Hl[0], xqB, xqA, lt + 1);
  }
#undef STEP
}

// --- K3 body (512 threads): heads GEMM from int8 hbuf; 2 k2-blocks per tile.
__device__ __forceinline__ void k3_body(int gk,
                                        const signed char* __restrict__ hbuf,
                                        const signed char* __restrict__ Wlq,
                                        const float* __restrict__ lsc,
                                        const float* __restrict__ blog,
                                        const float* __restrict__ bval,
                                        float* __restrict__ out,
                                        int t0, int tc, int tcsh) {
  const int w = threadIdx.x >> 6, l = threadIdx.x & 63;
  const int lc = l & 15, lq = l >> 4;
  const int tk = gk * 8 + w;                    // 0 .. 16*tc-1
  const int pg = tk >> tcsh, lt = tk & (tc - 1);
  const int t = t0 + lt;
  const int b = pg * 2 + (lc >> 3);             // k2 block holding this seq
  const i32x4 zero4 = {0, 0, 0, 0};

  i32x4 dacc[3] = {zero4, zero4, zero4};
  #pragma unroll
  for (int kk = 0; kk < 4; ++kk) {
    i32x4 a = *(const i32x4*)(hbuf + ((size_t)(b * tc + lt) * 8 + (lc & 7)) * 256
                              + kk * 64 + (lq << 4));
    #pragma unroll
    for (int n = 0; n < 3; ++n) {
      int row = n * 16 + lc;
      i32x4 bf = (row < 33) ? *(const i32x4*)(Wlq + (size_t)row * 256 + kk * 64 + (lq << 4))
                            : zero4;
      dacc[n] = __builtin_amdgcn_mfma_i32_16x16x64_i8(a, bf, dacc[n], 0, 0, 0);
    }
  }
  #pragma unroll
  for (int n = 0; n < 2; ++n) {
    float dsn = lsc[n * 16 + lc] * (1.f / 127.f);
    float lbn = blog[n * 16 + lc];
    #pragma unroll
    for (int r = 0; r < 4; ++r) {
      int sg = (pg << 4) + lq * 4 + r;
      out[((size_t)sg * 512 + t) * 32 + n * 16 + lc] = fmaf((float)dacc[n][r], dsn, lbn);
    }
  }
  if (lc == 0) {
    float ds2 = lsc[32] * (1.f / 127.f);
    float b2 = bval[0];
    #pragma unroll
    for (int r = 0; r < 4; ++r) {
      int sg = (pg << 4) + lq * 4 + r;
      out[4194304 + (size_t)sg * 512 + t] = fmaf((float)dacc[2][r], ds2, b2);
    }
  }
}

// ================================================================ MEGA
__launch_bounds__(512, 2)
__global__ void mega(int nk2, int t0_2, const unsigned short* xp2, signed char* hb2,
                     int nk1, int t0_1, unsigned short* xp1,
                     int nk3, int t0_3, const signed char* hb3,
                     const float* feat, const float* Wih,
                     const float* bih, const float* bhh,
                     const signed char* Wq, const float* wsc,
                     const signed char* Wlq, const float* lsc,
                     const float* ep, const float* h0, const float* c0,
                     const float* blog, const float* bval,
                     float* hstate, float* cstate, float* out,
                     int tc, int tcsh) {
  __shared__ __align__(16) char smem[53248];
  int bid = (int)blockIdx.x;
  if (bid < nk2) {
    k2_body(bid, smem, xp2, Wq, wsc, ep, h0, c0, hstate, cstate, hb2, out, t0_2, tc);
  } else if (bid < nk2 + nk1) {
    k1_body(bid - nk2, smem, feat, Wih, bih, bhh, xp1, t0_1);
  } else {
    k3_body(bid - nk2 - nk1, hb3, Wlq, lsc, blog, bval, out, t0_3, tc, tcsh);
  }
}

// ---------------------------------------------------------------- launcher
extern "C" void kernel_launch(void* const* d_in, const int* in_sizes, int n_in,
                              void* d_out, int out_size, void* d_ws, size_t ws_size,
                              hipStream_t stream) {
  const float* feat = (const float*)d_in[0];
  const float* ep   = (const float*)d_in[1];
  const float* h0   = (const float*)d_in[2];
  const float* c0   = (const float*)d_in[3];
  const float* Wih  = (const float*)d_in[4];
  const float* Whh  = (const float*)d_in[5];
  const float* bih  = (const float*)d_in[6];
  const float* bhh  = (const float*)d_in[7];
  const float* Wlog = (const float*)d_in[8];
  const float* blog = (const float*)d_in[9];
  const float* Wval = (const float*)d_in[10];
  const float* bval = (const float*)d_in[11];
  float* out = (float*)d_out;
  char* ws = (char*)d_ws;
  signed char* Wq     = (signed char*)(ws + 0);        // 262144
  float*       wsc    = (float*)      (ws + 262144);   // 4096
  signed char* Wlq    = (signed char*)(ws + 266240);   // 8448
  float*       lsc    = (float*)      (ws + 274688);   // 132
  float*       hstate = (float*)      (ws + 275456);   // 262144
  float*       cstate = (float*)      (ws + 537600);   // 262144 (ends 799744)

  // Tc chosen so 1MiB + 2*Tc*(512KiB xp + 16KiB hbuf) <= ws_size; Tc<=128.
  int Tc = 128;
  while (Tc > 16 && (size_t)1048576 + (size_t)Tc * 1179648 > ws_size) Tc >>= 1;
  int tcsh = 31 - __builtin_clz(Tc);
  int nc = 512 / Tc;
  size_t xpsz = (size_t)Tc * 524288, hbsz = (size_t)Tc * 65536;
  unsigned short* xpb[2] = { (unsigned short*)(ws + 1048576),
                             (unsigned short*)(ws + 1048576 + xpsz) };
  signed char*    hbb[2] = { (signed char*)(ws + 1048576 + 2 * xpsz),
                             (signed char*)(ws + 1048576 + 2 * xpsz + hbsz) };
  const int NK1 = Tc * 32;   // k1 tiles: (Tc*256/64) * 8
  const int NK3 = Tc * 2;    // k3: 16*Tc wave-tasks / 8 waves

  hipLaunchKernelGGL(k0_quant, dim3(1057), dim3(64), 0, stream,
                     Whh, Wlog, Wval, Wq, wsc, Wlq, lsc);
  // lead-in: k1 for chunk 0
  hipLaunchKernelGGL(mega, dim3(NK1), dim3(512), 0, stream,
                     0, 0, xpb[0], hbb[0],
                     NK1, 0, xpb[0],
                     0, 0, hbb[0],
                     feat, Wih, bih, bhh, Wq, wsc, Wlq, lsc, ep, h0, c0,
                     blog, bval, hstate, cstate, out, Tc, tcsh);
  for (int j = 0; j < nc; ++j) {
    int nk1 = (j + 1 < nc) ? NK1 : 0;
    int nk3 = (j >= 1) ? NK3 : 0;
    hipLaunchKernelGGL(mega, dim3(32 + nk1 + nk3), dim3(512), 0, stream,
                       32, j * Tc, xpb[j & 1], hbb[j & 1],
                       nk1, (j + 1) * Tc, xpb[(j + 1) & 1],
                       nk3, (j - 1) * Tc, hbb[(j + 1) & 1],   // (j-1)&1 == (j+1)&1
                       feat, Wih, bih, bhh, Wq, wsc, Wlq, lsc, ep, h0, c0,
                       blog, bval, hstate, cstate, out, Tc, tcsh);
  }
  // tail: k3 for last chunk
  hipLaunchKernelGGL(mega, dim3(NK3), dim3(512), 0, stream,
                     0, 0, xpb[0], hbb[0],
                     0, 0, xpb[0],
                     NK3, (nc - 1) * Tc, hbb[(nc - 1) & 1],
                     feat, Wih, bih, bhh, Wq, wsc, Wlq, lsc, ep, h0, c0,
                     blog, bval, hstate, cstate, out, Tc, tcsh);
}

// Round 7
// 802.983 us; speedup vs baseline: 2.7594x; 1.0739x over previous
//
#include <hip/hip_runtime.h>
#include <hip/hip_bf16.h>

// ACLSTM on MI355X — persistent-RNN, time-chunked + software-pipelined.
// R7: k1 rewrite (k2/k3 untouched from R6-PASS):
//     - block = 512 thr, tile M=128 x N=128 where N covers ALL 4 gates for
//       32 j-cols (c = jj*4+gm) -> each block writes contiguous block-exclusive
//       256B/row spans of xp: kills the 4x TCC partial-line write amplification
//       seen in R6 (WRITE_SIZE 275MB vs 81MB logical).
//     - A (feat) direct to registers per wave (no A-LDS, all threads active);
//       B (Wih 32KB) staged once per block; 256 MFMA/block.
//     - xp values bitwise-identical to R6 (same MFMA shapes/accum order).

typedef float f32x4 __attribute__((ext_vector_type(4)));
typedef int   i32x4 __attribute__((ext_vector_type(4)));
typedef short s16x8 __attribute__((ext_vector_type(8)));
typedef short s16x4 __attribute__((ext_vector_type(4)));
typedef unsigned short u16x4 __attribute__((ext_vector_type(4)));

#define L2E   1.44269504088896340736f
#define L2E2  2.88539008177792681472f

__device__ __forceinline__ float fexp2(float x) {
#if __has_builtin(__builtin_amdgcn_exp2f)
  return __builtin_amdgcn_exp2f(x);
#else
  float r; asm("v_exp_f32 %0, %1" : "=v"(r) : "v"(x)); return r;
#endif
}
__device__ __forceinline__ float frcp(float x) { return __builtin_amdgcn_rcpf(x); }
__device__ __forceinline__ float bf2f(unsigned short u) {
  return __uint_as_float(((unsigned)u) << 16);
}
__device__ __forceinline__ unsigned short f2bf(float f) {   // RNE f32->bf16
  unsigned int b = __float_as_uint(f);
  return (unsigned short)((b + 0x7FFFu + ((b >> 16) & 1u)) >> 16);
}

// ---------------------------------------------------------------- K0: quant
__global__ void k0_quant(const float* __restrict__ Whh,
                         const float* __restrict__ Wlog,
                         const float* __restrict__ Wval,
                         signed char* __restrict__ Wq, float* __restrict__ wsc,
                         signed char* __restrict__ Wlq, float* __restrict__ lsc) {
  int r = blockIdx.x, l = threadIdx.x;   // 1057 rows, 64 lanes
  const float* src; signed char* dst; float* sd;
  if (r < 1024) { src = Whh + (size_t)r * 256; dst = Wq + (size_t)r * 256; sd = wsc + r; }
  else {
    int hr = r - 1024;
    src = (hr < 32) ? (Wlog + (size_t)hr * 256) : Wval;
    dst = Wlq + (size_t)hr * 256; sd = lsc + hr;
  }
  f32x4 v = *(const f32x4*)(src + l * 4);
  float m = fmaxf(fmaxf(fabsf(v.x), fabsf(v.y)), fmaxf(fabsf(v.z), fabsf(v.w)));
  #pragma unroll
  for (int off = 32; off; off >>= 1) m = fmaxf(m, __shfl_xor(m, off));
  float inv = (m > 0.f) ? (127.f / m) : 0.f;
  int q0 = (int)rintf(v.x * inv), q1 = (int)rintf(v.y * inv);
  int q2 = (int)rintf(v.z * inv), q3 = (int)rintf(v.w * inv);
  unsigned int pk = (q0 & 255) | ((q1 & 255) << 8) | ((q2 & 255) << 16) | ((q3 & 255) << 24);
  *(unsigned int*)(dst + l * 4) = pk;
  if (l == 0) *sd = m * (1.f / 127.f);
}

// ================================================================ bodies
// --- K1 body v2 (512 threads): M=128 x N=128(=32j x 4gm), A in regs, B in LDS.
// col c = jj*4+gm, g(c) = (c&3)*256 + j0 + (c>>2); xp elem = m*1024 + j0*4 + c.
__device__ __forceinline__ void k1_body(int gk, char* smem,
                                        const float* __restrict__ feat,
                                        const float* __restrict__ Wih,
                                        const float* __restrict__ bih,
                                        const float* __restrict__ bhh,
                                        unsigned short* __restrict__ xp, int t0) {
  short (*Bl)[136] = (short (*)[136])smem;                  // 128x136 = 34816 B
  float* bias = (float*)(smem + 34816);                     // 512 B
  const int tid = threadIdx.x;
  const int bm = gk >> 3, bn = gk & 7;
  const int m0 = bm << 7, j0 = bn << 5;
  const int tg = t0 + (bm >> 1), sbase = (bm & 1) << 7;     // 128 | 256
  #pragma unroll
  for (int it = 0; it < 8; ++it) {             // B: 128 g-rows x 128 k
    int idx = it * 512 + tid;
    int rr = idx >> 5, c4 = (idx & 31) << 2;
    int g = ((rr & 3) << 8) + j0 + (rr >> 2);
    f32x4 v = *(const f32x4*)(Wih + (size_t)g * 128 + c4);
    s16x4 pk = { (short)f2bf(v.x), (short)f2bf(v.y), (short)f2bf(v.z), (short)f2bf(v.w) };
    *(s16x4*)&Bl[rr][c4] = pk;
  }
  if (tid < 128) {
    int g = ((tid & 3) << 8) + j0 + (tid >> 2);
    bias[tid] = bih[g] + bhh[g];
  }
  const int w = tid >> 6, l = tid & 63;
  const int lr = l & 15, lk8 = (l >> 4) << 3;
  // A: wave w rows m0 + w*16 + lr, direct f32->bf16 to regs.
  s16x8 a[4];
  {
    const float* fp = feat + ((size_t)(sbase + (w << 4) + lr) * 512 + tg) * 128 + lk8;
    #pragma unroll
    for (int kk = 0; kk < 4; ++kk) {
      f32x4 v0 = *(const f32x4*)(fp + kk * 32);
      f32x4 v1 = *(const f32x4*)(fp + kk * 32 + 4);
      s16x8 pk = { (short)f2bf(v0.x), (short)f2bf(v0.y), (short)f2bf(v0.z), (short)f2bf(v0.w),
                   (short)f2bf(v1.x), (short)f2bf(v1.y), (short)f2bf(v1.z), (short)f2bf(v1.w) };
      a[kk] = pk;
    }
  }
  __syncthreads();
  f32x4 z = {0.f, 0.f, 0.f, 0.f};
  f32x4 acc[8];
  #pragma unroll
  for (int nt = 0; nt < 8; ++nt) acc[nt] = z;
  #pragma unroll
  for (int kk = 0; kk < 4; ++kk) {
    #pragma unroll
    for (int nt = 0; nt < 8; ++nt) {
      s16x8 bb = *(const s16x8*)&Bl[nt * 16 + lr][kk * 32 + lk8];
      acc[nt] = __builtin_amdgcn_mfma_f32_16x16x32_bf16(a[kk], bb, acc[nt], 0, 0, 0);
    }
  }
  #pragma unroll
  for (int nt = 0; nt < 8; ++nt) {
    #pragma unroll
    for (int r = 0; r < 4; ++r) {
      int m = m0 + (w << 4) + (l >> 4) * 4 + r;   // chunk-local
      int c = nt * 16 + lr;
      float gsc = ((c & 3) == 2) ? L2E2 : -L2E;
      float val = (acc[nt][r] + bias[c]) * gsc;
      xp[(size_t)m * 1024 + (j0 << 2) + c] = f2bf(val);
    }
  }
}

// --- K2 body: 32 blocks x 8 seqs, tc steps, duplicated h rows (s and s+8).
__device__ __forceinline__ void k2_body(int bid, char* smem,
                                        const unsigned short* __restrict__ xp,
                                        const signed char* __restrict__ Wq,
                                        const float* __restrict__ wsc,
                                        const float* __restrict__ ep,
                                        const float* __restrict__ h0,
                                        const float* __restrict__ c0,
                                        float* __restrict__ hstate,
                                        float* __restrict__ cstate,
                                        signed char* __restrict__ hbuf,
                                        float* __restrict__ out, int t0, int tc) {
  __builtin_amdgcn_s_setprio(3);           // recurrence is the critical path
  signed char (*Hl)[16][272] = (signed char (*)[16][272])smem;  // 2x16x272=8704
  float* flgl = (float*)(smem + 8704);     // [lt][8] flags, tc*32 B
  const int tid = threadIdx.x;
  const int w = tid >> 6, l = tid & 63;
  const int lc = l & 15, lq = l >> 4;
  const int hf = lq >> 1;                  // which 16-col half of the wave's 32
  const int sb = (lq & 1) << 2;            // lane's seq base (0 or 4)
  const int j = (w << 5) + (hf << 4) + lc; // lane's h-column
  const int s0 = bid << 3;
  const bool last = (t0 + tc == 512);

  {                                        // stage h rows 0..15 (dup, unmasked)
    const float* hsrc = (t0 == 0) ? h0 : hstate;
    #pragma unroll
    for (int it = 0; it < 8; ++it) {
      int idx = it * 512 + tid;            // 0..4095
      int srow = idx >> 8, jj = idx & 255;
      float v = hsrc[(size_t)(s0 + (srow & 7)) * 256 + jj];
      float q = rintf(fminf(fmaxf(v * 127.f, -127.f), 127.f));
      Hl[0][srow][jj] = (signed char)(int)q;
    }
  }
  {                                        // stage episode flags [lt][8]
    int n = tc << 3;
    for (int idx = tid; idx < n; idx += 512) {
      int s = idx & 7, llt = idx >> 3;
      flgl[idx] = ep[(size_t)(s0 + s) * 512 + t0 + llt];
    }
  }

  i32x4 wq[8][4];                          // persistent int8 W_hh fragments
  #pragma unroll
  for (int tau = 0; tau < 8; ++tau) {
    int g = (tau >> 1) * 256 + (w << 5) + ((tau & 1) << 4) + lc;
    #pragma unroll
    for (int kk = 0; kk < 4; ++kk)
      wq[tau][kk] = *(const i32x4*)(Wq + (size_t)g * 256 + kk * 64 + (lq << 4));
  }
  float dsc[4];                            // consumer-lane dequant scales
  #pragma unroll
  for (int gamma = 0; gamma < 4; ++gamma) {
    float sgn = (gamma == 2) ? L2E2 : -L2E;
    dsc[gamma] = sgn * wsc[gamma * 256 + j] * (1.f / 127.f);
  }

  float cst[4];                            // c state fp32, seqs sb+0..3, col j
  {
    const float* csrc = (t0 == 0) ? c0 : cstate;
    #pragma unroll
    for (int r = 0; r < 4; ++r)
      cst[r] = csrc[(size_t)(s0 + sb + r) * 256 + j];
  }

  // xp per-lane elem offset: ((lt*256 + s)*256 + j)*4 ; s = s0+sb+r
  const size_t xoff = ((size_t)(s0 + sb) * 256 + j) * 4;
  u16x4 xqA[4], xqB[4];
  {
    const unsigned short* pp = xp + xoff;  // lt = 0
    #pragma unroll
    for (int r = 0; r < 4; ++r) xqA[r] = *(const u16x4*)(pp + r * 1024);
  }
  __syncthreads();                          // staging barrier (full, once)

  const int aoff  = lc * 272 + (lq << 4);  // A-frag lane offset (row: seq lc&7)
  const int hwoff = sb * 272 + j;          // h-write lane offset (LDS)
  const i32x4 zero4 = {0, 0, 0, 0};

#define STEP(HR, HWR, XC, XN, LT)                                              \
  {                                                                            \
    const int lt_ = (LT);                                                      \
    if (lt_ + 1 < tc) {                  /* early prefetch: next xp -> XN */   \
      const unsigned short* pp = xp + (size_t)(lt_ + 1) * 262144 + xoff;       \
      _Pragma("unroll")                                                        \
      for (int r = 0; r < 4; ++r) XN[r] = *(const u16x4*)(pp + r * 1024);      \
    }                                                                          \
    float fa = flgl[lt_ * 8 + (lc & 7)];   /* reset flag, A-row's seq */       \
    f32x4 frv = *(const f32x4*)&flgl[lt_ * 8 + sb];                            \
    i32x4 racc[8];                                                             \
    const signed char* hbase = &(HR)[0][0];                                    \
    {                                                                          \
      i32x4 a = *(const i32x4*)(hbase + aoff);                                 \
      i32x4 am = (fa != 0.f) ? zero4 : a;                                      \
      _Pragma("unroll")                                                        \
      for (int tau = 0; tau < 8; ++tau)                                        \
        racc[tau] = __builtin_amdgcn_mfma_i32_16x16x64_i8(am, wq[tau][0], zero4, 0, 0, 0); \
    }                                                                          \
    _Pragma("unroll")                                                          \
    for (int kk = 1; kk < 4; ++kk) {                                           \
      i32x4 a = *(const i32x4*)(hbase + aoff + kk * 64);                       \
      i32x4 am = (fa != 0.f) ? zero4 : a;                                      \
      _Pragma("unroll")                                                        \
      for (int tau = 0; tau < 8; ++tau)                                        \
        racc[tau] = __builtin_amdgcn_mfma_i32_16x16x64_i8(am, wq[tau][kk], racc[tau], 0, 0, 0); \
    }                                                                          \
    signed char* hw = &(HWR)[0][0];                                            \
    signed char* hb = hbuf + ((size_t)(bid * tc + lt_) * 8 + sb) * 256 + j;    \
    _Pragma("unroll")                                                          \
    for (int r = 0; r < 4; ++r) {                                              \
      int g0 = hf ? racc[1][r] : racc[0][r];   /* constant indices + select */ \
      int g1 = hf ? racc[3][r] : racc[2][r];                                   \
      int g2 = hf ? racc[5][r] : racc[4][r];                                   \
      int g3 = hf ? racc[7][r] : racc[6][r];                                   \
      u16x4 xv = XC[r];                                                        \
      float xi = fmaf((float)g0, dsc[0], bf2f(xv.x));                          \
      float xf = fmaf((float)g1, dsc[1], bf2f(xv.y));                          \
      float xg = fmaf((float)g2, dsc[2], bf2f(xv.z));                          \
      float xo = fmaf((float)g3, dsc[3], bf2f(xv.w));                          \
      float si = frcp(1.f + fexp2(xi));                                        \
      float sf = frcp(1.f + fexp2(xf));                                        \
      float so = frcp(1.f + fexp2(xo));                                        \
      float tg = fmaf(-2.f, frcp(1.f + fexp2(xg)), 1.f);                       \
      float cp = (frv[r] != 0.f) ? 0.f : cst[r];                               \
      float cn = fmaf(sf, cp, si * tg);                                        \
      cst[r] = cn;                                                             \
      float th = fmaf(-2.f, frcp(1.f + fexp2(L2E2 * cn)), 1.f);                \
      float hn = so * th;                                                      \
      signed char q8 = (signed char)(int)rintf(hn * 127.f);                    \
      hw[hwoff + r * 272] = q8;            /* row sb+r   */                    \
      hw[hwoff + r * 272 + 2176] = q8;     /* row sb+r+8 (dup) */              \
      hb[r * 256] = q8;                                                        \
      if (lt_ == tc - 1) {                                                     \
        int sg = s0 + sb + r;                                                  \
        hstate[(size_t)sg * 256 + j] = hn;                                     \
        cstate[(size_t)sg * 256 + j] = cn;                                     \
        if (last) {                                                            \
          out[4325376 + (size_t)sg * 256 + j] = hn;                            \
          out[4390912 + (size_t)sg * 256 + j] = cn;                            \
        }                                                                      \
      }                                                                        \
    }                                                                          \
    asm volatile("s_waitcnt lgkmcnt(0)\n\ts_barrier" ::: "memory");            \
  }

  for (int lt = 0; lt < tc; lt += 2) {     // tc even
    STEP(Hl[0], Hl[1], xqA, xqB, lt);
    STEP(Hl[1], Hl[0], xqB, xqA, lt + 1);
  }
#undef STEP
}

// --- K3 body (512 threads): heads GEMM from int8 hbuf; 2 k2-blocks per tile.
__device__ __forceinline__ void k3_body(int gk,
                                        const signed char* __restrict__ hbuf,
                                        const signed char* __restrict__ Wlq,
                                        const float* __restrict__ lsc,
                                        const float* __restrict__ blog,
                                        const float* __restrict__ bval,
                                        float* __restrict__ out,
                                        int t0, int tc, int tcsh) {
  const int w = threadIdx.x >> 6, l = threadIdx.x & 63;
  const int lc = l & 15, lq = l >> 4;
  const int tk = gk * 8 + w;                    // 0 .. 16*tc-1
  const int pg = tk >> tcsh, lt = tk & (tc - 1);
  const int t = t0 + lt;
  const int b = pg * 2 + (lc >> 3);             // k2 block holding this seq
  const i32x4 zero4 = {0, 0, 0, 0};

  i32x4 dacc[3] = {zero4, zero4, zero4};
  #pragma unroll
  for (int kk = 0; kk < 4; ++kk) {
    i32x4 a = *(const i32x4*)(hbuf + ((size_t)(b * tc + lt) * 8 + (lc & 7)) * 256
                              + kk * 64 + (lq << 4));
    #pragma unroll
    for (int n = 0; n < 3; ++n) {
      int row = n * 16 + lc;
      i32x4 bf = (row < 33) ? *(const i32x4*)(Wlq + (size_t)row * 256 + kk * 64 + (lq << 4))
                            : zero4;
      dacc[n] = __builtin_amdgcn_mfma_i32_16x16x64_i8(a, bf, dacc[n], 0, 0, 0);
    }
  }
  #pragma unroll
  for (int n = 0; n < 2; ++n) {
    float dsn = lsc[n * 16 + lc] * (1.f / 127.f);
    float lbn = blog[n * 16 + lc];
    #pragma unroll
    for (int r = 0; r < 4; ++r) {
      int sg = (pg << 4) + lq * 4 + r;
      out[((size_t)sg * 512 + t) * 32 + n * 16 + lc] = fmaf((float)dacc[n][r], dsn, lbn);
    }
  }
  if (lc == 0) {
    float ds2 = lsc[32] * (1.f / 127.f);
    float b2 = bval[0];
    #pragma unroll
    for (int r = 0; r < 4; ++r) {
      int sg = (pg << 4) + lq * 4 + r;
      out[4194304 + (size_t)sg * 512 + t] = fmaf((float)dacc[2][r], ds2, b2);
    }
  }
}

// ================================================================ MEGA
__launch_bounds__(512, 2)
__global__ void mega(int nk2, int t0_2, const unsigned short* xp2, signed char* hb2,
                     int nk1, int t0_1, unsigned short* xp1,
                     int nk3, int t0_3, const signed char* hb3,
                     const float* feat, const float* Wih,
                     const float* bih, const float* bhh,
                     const signed char* Wq, const float* wsc,
                     const signed char* Wlq, const float* lsc,
                     const float* ep, const float* h0, const float* c0,
                     const float* blog, const float* bval,
                     float* hstate, float* cstate, float* out,
                     int tc, int tcsh) {
  __shared__ __align__(16) char smem[35328];
  int bid = (int)blockIdx.x;
  if (bid < nk2) {
    k2_body(bid, smem, xp2, Wq, wsc, ep, h0, c0, hstate, cstate, hb2, out, t0_2, tc);
  } else if (bid < nk2 + nk1) {
    k1_body(bid - nk2, smem, feat, Wih, bih, bhh, xp1, t0_1);
  } else {
    k3_body(bid - nk2 - nk1, hb3, Wlq, lsc, blog, bval, out, t0_3, tc, tcsh);
  }
}

// ---------------------------------------------------------------- launcher
extern "C" void kernel_launch(void* const* d_in, const int* in_sizes, int n_in,
                              void* d_out, int out_size, void* d_ws, size_t ws_size,
                              hipStream_t stream) {
  const float* feat = (const float*)d_in[0];
  const float* ep   = (const float*)d_in[1];
  const float* h0   = (const float*)d_in[2];
  const float* c0   = (const float*)d_in[3];
  const float* Wih  = (const float*)d_in[4];
  const float* Whh  = (const float*)d_in[5];
  const float* bih  = (const float*)d_in[6];
  const float* bhh  = (const float*)d_in[7];
  const float* Wlog = (const float*)d_in[8];
  const float* blog = (const float*)d_in[9];
  const float* Wval = (const float*)d_in[10];
  const float* bval = (const float*)d_in[11];
  float* out = (float*)d_out;
  char* ws = (char*)d_ws;
  signed char* Wq     = (signed char*)(ws + 0);        // 262144
  float*       wsc    = (float*)      (ws + 262144);   // 4096
  signed char* Wlq    = (signed char*)(ws + 266240);   // 8448
  float*       lsc    = (float*)      (ws + 274688);   // 132
  float*       hstate = (float*)      (ws + 275456);   // 262144
  float*       cstate = (float*)      (ws + 537600);   // 262144 (ends 799744)

  // Tc chosen so 1MiB + 2*Tc*(512KiB xp + 16KiB hbuf) <= ws_size; Tc<=128.
  int Tc = 128;
  while (Tc > 16 && (size_t)1048576 + (size_t)Tc * 1179648 > ws_size) Tc >>= 1;
  int tcsh = 31 - __builtin_clz(Tc);
  int nc = 512 / Tc;
  size_t xpsz = (size_t)Tc * 524288, hbsz = (size_t)Tc * 65536;
  unsigned short* xpb[2] = { (unsigned short*)(ws + 1048576),
                             (unsigned short*)(ws + 1048576 + xpsz) };
  signed char*    hbb[2] = { (signed char*)(ws + 1048576 + 2 * xpsz),
                             (signed char*)(ws + 1048576 + 2 * xpsz + hbsz) };
  const int NK1 = Tc * 16;   // k1 tiles: (Tc*256/128 m-tiles) * 8 bn
  const int NK3 = Tc * 2;    // k3: 16*Tc wave-tasks / 8 waves

  hipLaunchKernelGGL(k0_quant, dim3(1057), dim3(64), 0, stream,
                     Whh, Wlog, Wval, Wq, wsc, Wlq, lsc);
  // lead-in: k1 for chunk 0
  hipLaunchKernelGGL(mega, dim3(NK1), dim3(512), 0, stream,
                     0, 0, xpb[0], hbb[0],
                     NK1, 0, xpb[0],
                     0, 0, hbb[0],
                     feat, Wih, bih, bhh, Wq, wsc, Wlq, lsc, ep, h0, c0,
                     blog, bval, hstate, cstate, out, Tc, tcsh);
  for (int j = 0; j < nc; ++j) {
    int nk1 = (j + 1 < nc) ? NK1 : 0;
    int nk3 = (j >= 1) ? NK3 : 0;
    hipLaunchKernelGGL(mega, dim3(32 + nk1 + nk3), dim3(512), 0, stream,
                       32, j * Tc, xpb[j & 1], hbb[j & 1],
                       nk1, (j + 1) * Tc, xpb[(j + 1) & 1],
                       nk3, (j - 1) * Tc, hbb[(j + 1) & 1],   // (j-1)&1 == (j+1)&1
                       feat, Wih, bih, bhh, Wq, wsc, Wlq, lsc, ep, h0, c0,
                       blog, bval, hstate, cstate, out, Tc, tcsh);
  }
  // tail: k3 for last chunk
  hipLaunchKernelGGL(mega, dim3(NK3), dim3(512), 0, stream,
                     0, 0, xpb[0], hbb[0],
                     0, 0, xpb[0],
                     NK3, (nc - 1) * Tc, hbb[(nc - 1) & 1],
                     feat, Wih, bih, bhh, Wq, wsc, Wlq, lsc, ep, h0, c0,
                     blog, bval, hstate, cstate, out, Tc, tcsh);
}

// Round 8
// 611.804 us; speedup vs baseline: 3.6217x; 1.3125x over previous
//
#include <hip/hip_runtime.h>
#include <hip/hip_bf16.h>

// ACLSTM on MI355X — persistent-RNN, time-chunked + software-pipelined.
// R8: k2 = 64 blocks x 4 seqs, 2 cells/lane (was 32x8, 4 cells):
//     - A-fragment reads LDS row (lc&3): replication by broadcast read, no
//       duplicated rows, Hl = [2][4][272], h-write = 2 bytes/lane.
//     - gate values picked by static-index double-cndmask (hf, odd) — no
//       shfl, no dynamic register indexing.
//     - hbuf layout [lt][s][j] (k3 reads contiguous 16-seq rows).
//     k1/k3 compute unchanged; k1 proven hidden (~10us lead-in).

typedef float f32x4 __attribute__((ext_vector_type(4)));
typedef int   i32x4 __attribute__((ext_vector_type(4)));
typedef short s16x8 __attribute__((ext_vector_type(8)));
typedef short s16x4 __attribute__((ext_vector_type(4)));
typedef unsigned short u16x4 __attribute__((ext_vector_type(4)));

#define L2E   1.44269504088896340736f
#define L2E2  2.88539008177792681472f

__device__ __forceinline__ float fexp2(float x) {
#if __has_builtin(__builtin_amdgcn_exp2f)
  return __builtin_amdgcn_exp2f(x);
#else
  float r; asm("v_exp_f32 %0, %1" : "=v"(r) : "v"(x)); return r;
#endif
}
__device__ __forceinline__ float frcp(float x) { return __builtin_amdgcn_rcpf(x); }
__device__ __forceinline__ float bf2f(unsigned short u) {
  return __uint_as_float(((unsigned)u) << 16);
}
__device__ __forceinline__ unsigned short f2bf(float f) {   // RNE f32->bf16
  unsigned int b = __float_as_uint(f);
  return (unsigned short)((b + 0x7FFFu + ((b >> 16) & 1u)) >> 16);
}

// ---------------------------------------------------------------- K0: quant
__global__ void k0_quant(const float* __restrict__ Whh,
                         const float* __restrict__ Wlog,
                         const float* __restrict__ Wval,
                         signed char* __restrict__ Wq, float* __restrict__ wsc,
                         signed char* __restrict__ Wlq, float* __restrict__ lsc) {
  int r = blockIdx.x, l = threadIdx.x;   // 1057 rows, 64 lanes
  const float* src; signed char* dst; float* sd;
  if (r < 1024) { src = Whh + (size_t)r * 256; dst = Wq + (size_t)r * 256; sd = wsc + r; }
  else {
    int hr = r - 1024;
    src = (hr < 32) ? (Wlog + (size_t)hr * 256) : Wval;
    dst = Wlq + (size_t)hr * 256; sd = lsc + hr;
  }
  f32x4 v = *(const f32x4*)(src + l * 4);
  float m = fmaxf(fmaxf(fabsf(v.x), fabsf(v.y)), fmaxf(fabsf(v.z), fabsf(v.w)));
  #pragma unroll
  for (int off = 32; off; off >>= 1) m = fmaxf(m, __shfl_xor(m, off));
  float inv = (m > 0.f) ? (127.f / m) : 0.f;
  int q0 = (int)rintf(v.x * inv), q1 = (int)rintf(v.y * inv);
  int q2 = (int)rintf(v.z * inv), q3 = (int)rintf(v.w * inv);
  unsigned int pk = (q0 & 255) | ((q1 & 255) << 8) | ((q2 & 255) << 16) | ((q3 & 255) << 24);
  *(unsigned int*)(dst + l * 4) = pk;
  if (l == 0) *sd = m * (1.f / 127.f);
}

// ================================================================ bodies
// --- K1 body v2 (512 threads): M=128 x N=128(=32j x 4gm), A in regs, B in LDS.
__device__ __forceinline__ void k1_body(int gk, char* smem,
                                        const float* __restrict__ feat,
                                        const float* __restrict__ Wih,
                                        const float* __restrict__ bih,
                                        const float* __restrict__ bhh,
                                        unsigned short* __restrict__ xp, int t0) {
  short (*Bl)[136] = (short (*)[136])smem;                  // 128x136 = 34816 B
  float* bias = (float*)(smem + 34816);                     // 512 B
  const int tid = threadIdx.x;
  const int bm = gk >> 3, bn = gk & 7;
  const int m0 = bm << 7, j0 = bn << 5;
  const int tg = t0 + (bm >> 1), sbase = (bm & 1) << 7;     // 128 | 256
  #pragma unroll
  for (int it = 0; it < 8; ++it) {             // B: 128 g-rows x 128 k
    int idx = it * 512 + tid;
    int rr = idx >> 5, c4 = (idx & 31) << 2;
    int g = ((rr & 3) << 8) + j0 + (rr >> 2);
    f32x4 v = *(const f32x4*)(Wih + (size_t)g * 128 + c4);
    s16x4 pk = { (short)f2bf(v.x), (short)f2bf(v.y), (short)f2bf(v.z), (short)f2bf(v.w) };
    *(s16x4*)&Bl[rr][c4] = pk;
  }
  if (tid < 128) {
    int g = ((tid & 3) << 8) + j0 + (tid >> 2);
    bias[tid] = bih[g] + bhh[g];
  }
  const int w = tid >> 6, l = tid & 63;
  const int lr = l & 15, lk8 = (l >> 4) << 3;
  s16x8 a[4];
  {
    const float* fp = feat + ((size_t)(sbase + (w << 4) + lr) * 512 + tg) * 128 + lk8;
    #pragma unroll
    for (int kk = 0; kk < 4; ++kk) {
      f32x4 v0 = *(const f32x4*)(fp + kk * 32);
      f32x4 v1 = *(const f32x4*)(fp + kk * 32 + 4);
      s16x8 pk = { (short)f2bf(v0.x), (short)f2bf(v0.y), (short)f2bf(v0.z), (short)f2bf(v0.w),
                   (short)f2bf(v1.x), (short)f2bf(v1.y), (short)f2bf(v1.z), (short)f2bf(v1.w) };
      a[kk] = pk;
    }
  }
  __syncthreads();
  f32x4 z = {0.f, 0.f, 0.f, 0.f};
  f32x4 acc[8];
  #pragma unroll
  for (int nt = 0; nt < 8; ++nt) acc[nt] = z;
  #pragma unroll
  for (int kk = 0; kk < 4; ++kk) {
    #pragma unroll
    for (int nt = 0; nt < 8; ++nt) {
      s16x8 bb = *(const s16x8*)&Bl[nt * 16 + lr][kk * 32 + lk8];
      acc[nt] = __builtin_amdgcn_mfma_f32_16x16x32_bf16(a[kk], bb, acc[nt], 0, 0, 0);
    }
  }
  #pragma unroll
  for (int nt = 0; nt < 8; ++nt) {
    #pragma unroll
    for (int r = 0; r < 4; ++r) {
      int m = m0 + (w << 4) + (l >> 4) * 4 + r;   // chunk-local
      int c = nt * 16 + lr;
      float gsc = ((c & 3) == 2) ? L2E2 : -L2E;
      float val = (acc[nt][r] + bias[c]) * gsc;
      xp[(size_t)m * 1024 + (j0 << 2) + c] = f2bf(val);
    }
  }
}

// --- K2 body: 64 blocks x 4 seqs, tc steps, 2 cells/lane.
__device__ __forceinline__ void k2_body(int bid, char* smem,
                                        const unsigned short* __restrict__ xp,
                                        const signed char* __restrict__ Wq,
                                        const float* __restrict__ wsc,
                                        const float* __restrict__ ep,
                                        const float* __restrict__ h0,
                                        const float* __restrict__ c0,
                                        float* __restrict__ hstate,
                                        float* __restrict__ cstate,
                                        signed char* __restrict__ hbuf,
                                        float* __restrict__ out, int t0, int tc) {
  __builtin_amdgcn_s_setprio(3);           // recurrence is the critical path
  signed char (*Hl)[4][272] = (signed char (*)[4][272])smem;  // 2x4x272 = 2176
  float* flgl = (float*)(smem + 2176);     // [lt][4] flags, tc*16 B
  const int tid = threadIdx.x;
  const int w = tid >> 6, l = tid & 63;
  const int lc = l & 15, lq = l >> 4;
  const int hf = lq >> 1;                  // which 16-col half of the wave's 32
  const int odd = lq & 1;                  // which seq pair
  const int sb2 = odd << 1;                // lane's seq base (0 or 2)
  const int j = (w << 5) + (hf << 4) + lc; // lane's h-column
  const int s0 = bid << 2;
  const bool last = (t0 + tc == 512);

  {                                        // stage h rows 0..3 (int8, unmasked)
    const float* hsrc = (t0 == 0) ? h0 : hstate;
    #pragma unroll
    for (int it = 0; it < 2; ++it) {
      int idx = it * 512 + tid;            // 0..1023
      int s = idx >> 8, jj = idx & 255;
      float v = hsrc[(size_t)(s0 + s) * 256 + jj];
      float q = rintf(fminf(fmaxf(v * 127.f, -127.f), 127.f));
      Hl[0][s][jj] = (signed char)(int)q;
    }
  }
  {                                        // stage episode flags [lt][4]
    int n = tc << 2;
    for (int idx = tid; idx < n; idx += 512) {
      int s = idx & 3, llt = idx >> 2;
      flgl[idx] = ep[(size_t)(s0 + s) * 512 + t0 + llt];
    }
  }

  i32x4 wq[8][4];                          // persistent int8 W_hh fragments
  #pragma unroll
  for (int tau = 0; tau < 8; ++tau) {
    int g = (tau >> 1) * 256 + (w << 5) + ((tau & 1) << 4) + lc;
    #pragma unroll
    for (int kk = 0; kk < 4; ++kk)
      wq[tau][kk] = *(const i32x4*)(Wq + (size_t)g * 256 + kk * 64 + (lq << 4));
  }
  float dsc[4];                            // consumer-lane dequant scales
  #pragma unroll
  for (int gamma = 0; gamma < 4; ++gamma) {
    float sgn = (gamma == 2) ? L2E2 : -L2E;
    dsc[gamma] = sgn * wsc[gamma * 256 + j] * (1.f / 127.f);
  }

  float cst[2];                            // c state fp32, seqs s0+sb2+{0,1}
  {
    const float* csrc = (t0 == 0) ? c0 : cstate;
    #pragma unroll
    for (int cc = 0; cc < 2; ++cc)
      cst[cc] = csrc[(size_t)(s0 + sb2 + cc) * 256 + j];
  }

  // xp per-lane elem offset: ((lt*256 + s)*256 + j)*4 ; s = s0+sb2+cc
  const size_t xoff = ((size_t)(s0 + sb2) * 256 + j) * 4;
  u16x4 xqA[2], xqB[2];
  {
    const unsigned short* pp = xp + xoff;  // lt = 0
    #pragma unroll
    for (int cc = 0; cc < 2; ++cc) xqA[cc] = *(const u16x4*)(pp + cc * 1024);
  }
  __syncthreads();                          // staging barrier (full, once)

  const int aoff = (lc & 3) * 272 + (lq << 4);  // A-frag: row lc -> seq lc&3 (bcast)
  const i32x4 zero4 = {0, 0, 0, 0};

#define STEP(HR, HWR, XC, XN, LT)                                              \
  {                                                                            \
    const int lt_ = (LT);                                                      \
    if (lt_ + 1 < tc) {                  /* early prefetch: next xp -> XN */   \
      const unsigned short* pp = xp + (size_t)(lt_ + 1) * 262144 + xoff;       \
      _Pragma("unroll")                                                        \
      for (int cc = 0; cc < 2; ++cc) XN[cc] = *(const u16x4*)(pp + cc * 1024); \
    }                                                                          \
    float fa = flgl[lt_ * 4 + (lc & 3)];   /* reset flag, A-row's seq */       \
    i32x4 racc[8];                                                             \
    const signed char* hbase = &(HR)[0][0];                                    \
    {                                                                          \
      i32x4 a = *(const i32x4*)(hbase + aoff);                                 \
      i32x4 am = (fa != 0.f) ? zero4 : a;                                      \
      _Pragma("unroll")                                                        \
      for (int tau = 0; tau < 8; ++tau)                                        \
        racc[tau] = __builtin_amdgcn_mfma_i32_16x16x64_i8(am, wq[tau][0], zero4, 0, 0, 0); \
    }                                                                          \
    _Pragma("unroll")                                                          \
    for (int kk = 1; kk < 4; ++kk) {                                           \
      i32x4 a = *(const i32x4*)(hbase + aoff + kk * 64);                       \
      i32x4 am = (fa != 0.f) ? zero4 : a;                                      \
      _Pragma("unroll")                                                        \
      for (int tau = 0; tau < 8; ++tau)                                        \
        racc[tau] = __builtin_amdgcn_mfma_i32_16x16x64_i8(am, wq[tau][kk], racc[tau], 0, 0, 0); \
    }                                                                          \
    i32x4 sg0 = hf ? racc[1] : racc[0];    /* static-index selects only */     \
    i32x4 sg1 = hf ? racc[3] : racc[2];                                        \
    i32x4 sg2 = hf ? racc[5] : racc[4];                                        \
    i32x4 sg3 = hf ? racc[7] : racc[6];                                        \
    signed char* hw = &(HWR)[0][0];                                            \
    signed char* hb = hbuf + ((size_t)lt_ * 256 + (s0 + sb2)) * 256 + j;       \
    _Pragma("unroll")                                                          \
    for (int cc = 0; cc < 2; ++cc) {                                           \
      int g0 = odd ? sg0[2 + cc] : sg0[cc];                                    \
      int g1 = odd ? sg1[2 + cc] : sg1[cc];                                    \
      int g2 = odd ? sg2[2 + cc] : sg2[cc];                                    \
      int g3 = odd ? sg3[2 + cc] : sg3[cc];                                    \
      u16x4 xv = XC[cc];                                                       \
      float xi = fmaf((float)g0, dsc[0], bf2f(xv.x));                          \
      float xf = fmaf((float)g1, dsc[1], bf2f(xv.y));                          \
      float xg = fmaf((float)g2, dsc[2], bf2f(xv.z));                          \
      float xo = fmaf((float)g3, dsc[3], bf2f(xv.w));                          \
      float si = frcp(1.f + fexp2(xi));                                        \
      float sf = frcp(1.f + fexp2(xf));                                        \
      float so = frcp(1.f + fexp2(xo));                                        \
      float tg = fmaf(-2.f, frcp(1.f + fexp2(xg)), 1.f);                       \
      float fr = flgl[lt_ * 4 + sb2 + cc];                                     \
      float cp = (fr != 0.f) ? 0.f : cst[cc];                                  \
      float cn = fmaf(sf, cp, si * tg);                                        \
      cst[cc] = cn;                                                            \
      float th = fmaf(-2.f, frcp(1.f + fexp2(L2E2 * cn)), 1.f);                \
      float hn = so * th;                                                      \
      signed char q8 = (signed char)(int)rintf(hn * 127.f);                    \
      hw[(sb2 + cc) * 272 + j] = q8;                                           \
      hb[cc * 256] = q8;                                                       \
      if (lt_ == tc - 1) {                                                     \
        int sg = s0 + sb2 + cc;                                                \
        hstate[(size_t)sg * 256 + j] = hn;                                     \
        cstate[(size_t)sg * 256 + j] = cn;                                     \
        if (last) {                                                            \
          out[4325376 + (size_t)sg * 256 + j] = hn;                            \
          out[4390912 + (size_t)sg * 256 + j] = cn;                            \
        }                                                                      \
      }                                                                        \
    }                                                                          \
    asm volatile("s_waitcnt lgkmcnt(0)\n\ts_barrier" ::: "memory");            \
  }

  for (int lt = 0; lt < tc; lt += 2) {     // tc even
    STEP(Hl[0], Hl[1], xqA, xqB, lt);
    STEP(Hl[1], Hl[0], xqB, xqA, lt + 1);
  }
#undef STEP
}

// --- K3 body (512 threads): heads GEMM from int8 hbuf [lt][s][j].
__device__ __forceinline__ void k3_body(int gk,
                                        const signed char* __restrict__ hbuf,
                                        const signed char* __restrict__ Wlq,
                                        const float* __restrict__ lsc,
                                        const float* __restrict__ blog,
                                        const float* __restrict__ bval,
                                        float* __restrict__ out,
                                        int t0, int tc, int tcsh) {
  const int w = threadIdx.x >> 6, l = threadIdx.x & 63;
  const int lc = l & 15, lq = l >> 4;
  const int tk = gk * 8 + w;                    // 0 .. 16*tc-1
  const int pg = tk >> tcsh, lt = tk & (tc - 1);
  const int t = t0 + lt;
  const i32x4 zero4 = {0, 0, 0, 0};

  i32x4 dacc[3] = {zero4, zero4, zero4};
  #pragma unroll
  for (int kk = 0; kk < 4; ++kk) {
    i32x4 a = *(const i32x4*)(hbuf + ((size_t)lt * 256 + (pg << 4) + lc) * 256
                              + kk * 64 + (lq << 4));
    #pragma unroll
    for (int n = 0; n < 3; ++n) {
      int row = n * 16 + lc;
      i32x4 bf = (row < 33) ? *(const i32x4*)(Wlq + (size_t)row * 256 + kk * 64 + (lq << 4))
                            : zero4;
      dacc[n] = __builtin_amdgcn_mfma_i32_16x16x64_i8(a, bf, dacc[n], 0, 0, 0);
    }
  }
  #pragma unroll
  for (int n = 0; n < 2; ++n) {
    float dsn = lsc[n * 16 + lc] * (1.f / 127.f);
    float lbn = blog[n * 16 + lc];
    #pragma unroll
    for (int r = 0; r < 4; ++r) {
      int sg = (pg << 4) + lq * 4 + r;
      out[((size_t)sg * 512 + t) * 32 + n * 16 + lc] = fmaf((float)dacc[n][r], dsn, lbn);
    }
  }
  if (lc == 0) {
    float ds2 = lsc[32] * (1.f / 127.f);
    float b2 = bval[0];
    #pragma unroll
    for (int r = 0; r < 4; ++r) {
      int sg = (pg << 4) + lq * 4 + r;
      out[4194304 + (size_t)sg * 512 + t] = fmaf((float)dacc[2][r], ds2, b2);
    }
  }
}

// ================================================================ MEGA
__launch_bounds__(512, 2)
__global__ void mega(int nk2, int t0_2, const unsigned short* xp2, signed char* hb2,
                     int nk1, int t0_1, unsigned short* xp1,
                     int nk3, int t0_3, const signed char* hb3,
                     const float* feat, const float* Wih,
                     const float* bih, const float* bhh,
                     const signed char* Wq, const float* wsc,
                     const signed char* Wlq, const float* lsc,
                     const float* ep, const float* h0, const float* c0,
                     const float* blog, const float* bval,
                     float* hstate, float* cstate, float* out,
                     int tc, int tcsh) {
  __shared__ __align__(16) char smem[35328];
  int bid = (int)blockIdx.x;
  if (bid < nk2) {
    k2_body(bid, smem, xp2, Wq, wsc, ep, h0, c0, hstate, cstate, hb2, out, t0_2, tc);
  } else if (bid < nk2 + nk1) {
    k1_body(bid - nk2, smem, feat, Wih, bih, bhh, xp1, t0_1);
  } else {
    k3_body(bid - nk2 - nk1, hb3, Wlq, lsc, blog, bval, out, t0_3, tc, tcsh);
  }
}

// ---------------------------------------------------------------- launcher
extern "C" void kernel_launch(void* const* d_in, const int* in_sizes, int n_in,
                              void* d_out, int out_size, void* d_ws, size_t ws_size,
                              hipStream_t stream) {
  const float* feat = (const float*)d_in[0];
  const float* ep   = (const float*)d_in[1];
  const float* h0   = (const float*)d_in[2];
  const float* c0   = (const float*)d_in[3];
  const float* Wih  = (const float*)d_in[4];
  const float* Whh  = (const float*)d_in[5];
  const float* bih  = (const float*)d_in[6];
  const float* bhh  = (const float*)d_in[7];
  const float* Wlog = (const float*)d_in[8];
  const float* blog = (const float*)d_in[9];
  const float* Wval = (const float*)d_in[10];
  const float* bval = (const float*)d_in[11];
  float* out = (float*)d_out;
  char* ws = (char*)d_ws;
  signed char* Wq     = (signed char*)(ws + 0);        // 262144
  float*       wsc    = (float*)      (ws + 262144);   // 4096
  signed char* Wlq    = (signed char*)(ws + 266240);   // 8448
  float*       lsc    = (float*)      (ws + 274688);   // 132
  float*       hstate = (float*)      (ws + 275456);   // 262144
  float*       cstate = (float*)      (ws + 537600);   // 262144 (ends 799744)

  // Tc chosen so 1MiB + 2*Tc*(512KiB xp + 64KiB hbuf) <= ws_size; Tc<=128.
  int Tc = 128;
  while (Tc > 16 && (size_t)1048576 + (size_t)Tc * 1179648 > ws_size) Tc >>= 1;
  int tcsh = 31 - __builtin_clz(Tc);
  int nc = 512 / Tc;
  size_t xpsz = (size_t)Tc * 524288, hbsz = (size_t)Tc * 65536;
  unsigned short* xpb[2] = { (unsigned short*)(ws + 1048576),
                             (unsigned short*)(ws + 1048576 + xpsz) };
  signed char*    hbb[2] = { (signed char*)(ws + 1048576 + 2 * xpsz),
                             (signed char*)(ws + 1048576 + 2 * xpsz + hbsz) };
  const int NK1 = Tc * 16;   // k1 tiles: (Tc*256/128 m-tiles) * 8 bn
  const int NK3 = Tc * 2;    // k3: 16*Tc wave-tasks / 8 waves
  const int NK2 = 64;

  hipLaunchKernelGGL(k0_quant, dim3(1057), dim3(64), 0, stream,
                     Whh, Wlog, Wval, Wq, wsc, Wlq, lsc);
  // lead-in: k1 for chunk 0
  hipLaunchKernelGGL(mega, dim3(NK1), dim3(512), 0, stream,
                     0, 0, xpb[0], hbb[0],
                     NK1, 0, xpb[0],
                     0, 0, hbb[0],
                     feat, Wih, bih, bhh, Wq, wsc, Wlq, lsc, ep, h0, c0,
                     blog, bval, hstate, cstate, out, Tc, tcsh);
  for (int j = 0; j < nc; ++j) {
    int nk1 = (j + 1 < nc) ? NK1 : 0;
    int nk3 = (j >= 1) ? NK3 : 0;
    hipLaunchKernelGGL(mega, dim3(NK2 + nk1 + nk3), dim3(512), 0, stream,
                       NK2, j * Tc, xpb[j & 1], hbb[j & 1],
                       nk1, (j + 1) * Tc, xpb[(j + 1) & 1],
                       nk3, (j - 1) * Tc, hbb[(j + 1) & 1],   // (j-1)&1 == (j+1)&1
                       feat, Wih, bih, bhh, Wq, wsc, Wlq, lsc, ep, h0, c0,
                       blog, bval, hstate, cstate, out, Tc, tcsh);
  }
  // tail: k3 for last chunk
  hipLaunchKernelGGL(mega, dim3(NK3), dim3(512), 0, stream,
                     0, 0, xpb[0], hbb[0],
                     0, 0, xpb[0],
                     NK3, (nc - 1) * Tc, hbb[(nc - 1) & 1],
                     feat, Wih, bih, bhh, Wq, wsc, Wlq, lsc, ep, h0, c0,
                     blog, bval, hstate, cstate, out, Tc, tcsh);
}